// Round 1
// baseline (5696.756 us; speedup 1.0000x reference)
//
#include <hip/hip_runtime.h>
#include <stdint.h>
#include <stddef.h>

// LSTM: B=64, H=1024, V=4096, T=256
// Phase 0: transpose weights to bf16 k-contiguous layouts.
// Phase 1: 256 per-step MFMA gate kernels (launch boundary = sync).
// Phase 2: one big 16384x4096x1024 bf16 GEMM for Y.
// Workspace: WcatT 8MB | ywT 8MB | Hbuf (257*64*1024 bf16) 33.7MB | Cbuf 256KB  => ~50.7MB

#define B_ 64
#define H_ 1024
#define V_ 4096
#define T_ 256

typedef __attribute__((ext_vector_type(8))) short short8;
typedef __attribute__((ext_vector_type(4))) float f32x4;
typedef __attribute__((ext_vector_type(4))) float float4_;

static __device__ __forceinline__ unsigned short f2bf(float f) {
  union { float f; unsigned int u; } v; v.f = f;
  unsigned int u = v.u;
  unsigned int r = (u + 0x7fffu + ((u >> 16) & 1u)) >> 16;   // round-to-nearest-even
  return (unsigned short)r;
}
static __device__ __forceinline__ float bf2f(unsigned short s) {
  union { unsigned int u; float f; } v; v.u = ((unsigned int)s) << 16;
  return v.f;
}

static __device__ __forceinline__ void gload_lds16(const void* g, void* l) {
  // async global->LDS, 16B per lane; LDS dest = wave-uniform base + lane*16
  __builtin_amdgcn_global_load_lds((const __attribute__((address_space(1))) unsigned int*)g,
                                   (__attribute__((address_space(3))) unsigned int*)l,
                                   16, 0, 0);
}

// ---------------------------------------------------------------------------
// Tiled transpose fp32 (K x C) -> bf16 rows: dst[c = col*c_mul + c_add][k]
// grid: (K/64, C/64), 256 threads
// ---------------------------------------------------------------------------
__global__ void transpose_bf16_kernel(const float* __restrict__ src, int src_cols,
                                      unsigned short* __restrict__ dst,
                                      int c_mul, int c_add) {
  __shared__ float tile[64][65];
  const int k0 = blockIdx.x * 64, h0 = blockIdx.y * 64;
  const int t = threadIdx.x;
  {
    const int kk = t >> 2, seg = (t & 3) * 16;
    const float* s = src + (size_t)(k0 + kk) * src_cols + h0 + seg;
#pragma unroll
    for (int j = 0; j < 16; j += 4) {
      float4_ v = *(const float4_*)(s + j);
      tile[kk][seg + j + 0] = v[0];
      tile[kk][seg + j + 1] = v[1];
      tile[kk][seg + j + 2] = v[2];
      tile[kk][seg + j + 3] = v[3];
    }
  }
  __syncthreads();
  {
    const int hh = t >> 2, ks = (t & 3) * 16;
    const int c = (h0 + hh) * c_mul + c_add;
    short8 p0, p1;
#pragma unroll
    for (int j = 0; j < 8; ++j) {
      p0[j] = (short)f2bf(tile[ks + j][hh]);
      p1[j] = (short)f2bf(tile[ks + 8 + j][hh]);
    }
    unsigned short* d = dst + (size_t)c * 1024 + k0 + ks;
    *(short8*)(d) = p0;
    *(short8*)(d + 8) = p1;
  }
}

// ---------------------------------------------------------------------------
__global__ void init_kernel(const float* __restrict__ H0, const float* __restrict__ C0,
                            unsigned short* __restrict__ Hbuf0, float* __restrict__ Cbuf) {
  const int i = blockIdx.x * 256 + threadIdx.x;  // 65536
  Hbuf0[i] = f2bf(H0[i]);
  Cbuf[i] = C0[i];
}

// ---------------------------------------------------------------------------
// One LSTM step. Grid: 64 WGs x 256 thr. WG owns 64 gate-columns (c = h*4+g).
// A = Hin (64x1024 bf16), B = WcatT rows [wgc0..wgc0+64) (k-contiguous).
// ---------------------------------------------------------------------------
__launch_bounds__(256, 1)
__global__ void lstm_step_kernel(const unsigned short* __restrict__ Wc,   // [4096][1024] bf16
                                 const unsigned short* __restrict__ Hin,  // [64][1024] bf16
                                 unsigned short* __restrict__ Hout,       // [64][1024] bf16
                                 float* __restrict__ Cbuf,                // [64][1024] f32 in-place
                                 const float* __restrict__ xwf, const float* __restrict__ xwi,
                                 const float* __restrict__ xwc, const float* __restrict__ xwo,
                                 const float* __restrict__ bfv, const float* __restrict__ biv,
                                 const float* __restrict__ bcv, const float* __restrict__ bov,
                                 const int* __restrict__ tokens, int t) {
  __shared__ unsigned char Ash[2][8192];   // 64 rows x 128B (64 k-chunk, bf16), XOR-swizzled
  __shared__ unsigned char Bsh[2][8192];
  const int tid = threadIdx.x;
  const int wave = tid >> 6, lane = tid & 63;
  const int wm = wave >> 1, wn = wave & 1;
  const int wgc0 = blockIdx.x * 64;

  const char* Agb = (const char*)Hin;                          // row stride 2048B
  const char* Bgb = (const char*)(Wc + (size_t)wgc0 * 1024);   // row stride 2048B

  f32x4 acc[2][2];
  const f32x4 zz = {0.f, 0.f, 0.f, 0.f};
#pragma unroll
  for (int mi = 0; mi < 2; ++mi)
#pragma unroll
    for (int ni = 0; ni < 2; ++ni) acc[mi][ni] = zz;

  auto stage = [&](int buf, int kc) {
#pragma unroll
    for (int j = 0; j < 2; ++j) {
      const int wbase = wave * 2048 + j * 1024;   // wave-uniform byte base in 8KB tile
      const int D = wbase + lane * 16;            // this lane's dest byte
      const int row = D >> 7, off = D & 127;
      const int so = off ^ ((row & 7) << 4);      // pre-swizzled global source (rule #21)
      gload_lds16(Agb + (size_t)row * 2048 + kc * 128 + so, &Ash[buf][wbase]);
      gload_lds16(Bgb + (size_t)row * 2048 + kc * 128 + so, &Bsh[buf][wbase]);
    }
  };

  stage(0, 0);
  __syncthreads();

#pragma unroll 1
  for (int kc = 0; kc < 16; ++kc) {
    const int cur = kc & 1;
    if (kc < 15) stage(cur ^ 1, kc + 1);
#pragma unroll
    for (int ks = 0; ks < 2; ++ks) {
      short8 a[2], b[2];
#pragma unroll
      for (int mi = 0; mi < 2; ++mi) {
        const int row = wm * 32 + mi * 16 + (lane & 15);
        const int off = (ks * 64 + (lane >> 4) * 16) ^ ((row & 7) << 4);
        a[mi] = *(const short8*)&Ash[cur][row * 128 + off];
      }
#pragma unroll
      for (int ni = 0; ni < 2; ++ni) {
        const int row = wn * 32 + ni * 16 + (lane & 15);
        const int off = (ks * 64 + (lane >> 4) * 16) ^ ((row & 7) << 4);
        b[ni] = *(const short8*)&Bsh[cur][row * 128 + off];
      }
#pragma unroll
      for (int mi = 0; mi < 2; ++mi)
#pragma unroll
        for (int ni = 0; ni < 2; ++ni)
          acc[mi][ni] = __builtin_amdgcn_mfma_f32_16x16x32_bf16(a[mi], b[ni], acc[mi][ni], 0, 0, 0);
    }
    __syncthreads();
  }

  // epilogue: pre-activation -> gates -> C/H update.
  // D layout (m89): col = lane&15, row = (lane>>4)*4 + r. c = h*4+g so 4
  // adjacent lanes hold f,i,c,o of the same h -> shuffle-combine.
  const int l15 = lane & 15, l4 = lane >> 4;
#pragma unroll
  for (int mi = 0; mi < 2; ++mi) {
#pragma unroll
    for (int ni = 0; ni < 2; ++ni) {
      const f32x4 v = acc[mi][ni];
      const int col = wgc0 + wn * 32 + ni * 16 + l15;
      const int h = col >> 2, g = col & 3;
      const float* xw = (g == 0) ? xwf : (g == 1) ? xwi : (g == 2) ? xwc : xwo;
      const float* bb = (g == 0) ? bfv : (g == 1) ? biv : (g == 2) ? bcv : bov;
      const float bias = bb[h];
#pragma unroll
      for (int r = 0; r < 4; ++r) {
        const int brow = wm * 32 + mi * 16 + l4 * 4 + r;
        const int tok = tokens[brow * T_ + t];
        const float pre = v[r] + xw[(size_t)tok * 1024 + h] + bias;
        const float p1 = __shfl_down(pre, 1);
        const float p2 = __shfl_down(pre, 2);
        const float p3 = __shfl_down(pre, 3);
        if ((lane & 3) == 0) {
          const float pf = 1.f / (1.f + __expf(-pre));
          const float pi = 1.f / (1.f + __expf(-p1));
          const float e2 = __expf(2.f * p2);
          const float pc = (e2 - 1.f) / (e2 + 1.f);
          const float po = 1.f / (1.f + __expf(-p3));
          const size_t idx = (size_t)brow * 1024 + h;
          const float cn = pf * Cbuf[idx] + pi * pc;
          Cbuf[idx] = cn;
          Hout[idx] = f2bf(po * cn);
        }
      }
    }
  }
}

// ---------------------------------------------------------------------------
// Y = Hseq(16384x1024 bf16) @ ywT^T + bias -> fp32. m97-style 128x128, BK=32.
// grid: 4096 WGs (tm = id>>5, tn = id&31), 256 thr, waves 2x2, wave tile 64x64.
// ---------------------------------------------------------------------------
__launch_bounds__(256, 1)
__global__ void out_gemm_kernel(const unsigned short* __restrict__ A,   // [16384][1024] bf16
                                const unsigned short* __restrict__ Bw,  // ywT [4096][1024] bf16
                                const float* __restrict__ bias,         // [4096]
                                float* __restrict__ Yout) {             // [16384][4096] f32
  __shared__ unsigned char Ash[2][8192];   // 128 rows x 64B, XOR-swizzled
  __shared__ unsigned char Bsh[2][8192];
  const int tid = threadIdx.x;
  const int wave = tid >> 6, lane = tid & 63;
  const int wm = wave >> 1, wn = wave & 1;
  const int bid = blockIdx.x;
  const int tn = bid & 31, tm = bid >> 5;

  const char* Agb = (const char*)(A + (size_t)tm * 128 * 1024);
  const char* Bgb = (const char*)(Bw + (size_t)tn * 128 * 1024);

  f32x4 acc[4][4];
  const f32x4 zz = {0.f, 0.f, 0.f, 0.f};
#pragma unroll
  for (int mi = 0; mi < 4; ++mi)
#pragma unroll
    for (int ni = 0; ni < 4; ++ni) acc[mi][ni] = zz;

  auto stage = [&](int buf, int kc) {
#pragma unroll
    for (int j = 0; j < 2; ++j) {
      const int wbase = wave * 2048 + j * 1024;
      const int D = wbase + lane * 16;
      const int row = D >> 6, off = D & 63;
      const int so = off ^ ((row & 3) << 4);
      gload_lds16(Agb + (size_t)row * 2048 + kc * 64 + so, &Ash[buf][wbase]);
      gload_lds16(Bgb + (size_t)row * 2048 + kc * 64 + so, &Bsh[buf][wbase]);
    }
  };

  stage(0, 0);
  __syncthreads();

#pragma unroll 1
  for (int kc = 0; kc < 32; ++kc) {
    const int cur = kc & 1;
    if (kc < 31) stage(cur ^ 1, kc + 1);
    short8 a[4], b[4];
#pragma unroll
    for (int mi = 0; mi < 4; ++mi) {
      const int row = wm * 64 + mi * 16 + (lane & 15);
      const int off = ((lane >> 4) * 16) ^ ((row & 3) << 4);
      a[mi] = *(const short8*)&Ash[cur][row * 64 + off];
    }
#pragma unroll
    for (int ni = 0; ni < 4; ++ni) {
      const int row = wn * 64 + ni * 16 + (lane & 15);
      const int off = ((lane >> 4) * 16) ^ ((row & 3) << 4);
      b[ni] = *(const short8*)&Bsh[cur][row * 64 + off];
    }
#pragma unroll
    for (int mi = 0; mi < 4; ++mi)
#pragma unroll
      for (int ni = 0; ni < 4; ++ni)
        acc[mi][ni] = __builtin_amdgcn_mfma_f32_16x16x32_bf16(a[mi], b[ni], acc[mi][ni], 0, 0, 0);
    __syncthreads();
  }

  const int l15 = lane & 15, l4 = lane >> 4;
#pragma unroll
  for (int ni = 0; ni < 4; ++ni) {
    const int n = tn * 128 + wn * 64 + ni * 16 + l15;
    const float bv = bias[n];
#pragma unroll
    for (int mi = 0; mi < 4; ++mi) {
#pragma unroll
      for (int r = 0; r < 4; ++r) {
        const int m = tm * 128 + wm * 64 + mi * 16 + l4 * 4 + r;
        Yout[(size_t)m * 4096 + n] = acc[mi][ni][r] + bv;
      }
    }
  }
}

// ---------------------------------------------------------------------------
__global__ void final_kernel(const unsigned short* __restrict__ HT, const float* __restrict__ Cbuf,
                             float* __restrict__ outH, float* __restrict__ outC) {
  const int i = blockIdx.x * 256 + threadIdx.x;  // 65536
  outH[i] = bf2f(HT[i]);
  outC[i] = Cbuf[i];
}

// ---------------------------------------------------------------------------
extern "C" void kernel_launch(void* const* d_in, const int* in_sizes, int n_in,
                              void* d_out, int out_size, void* d_ws, size_t ws_size,
                              hipStream_t stream) {
  const int* tokens   = (const int*)d_in[0];
  const float* H0     = (const float*)d_in[1];
  const float* C0     = (const float*)d_in[2];
  const float* f_w_xh = (const float*)d_in[3];
  const float* f_w_hh = (const float*)d_in[4];
  const float* f_b    = (const float*)d_in[5];
  const float* i_w_xh = (const float*)d_in[6];
  const float* i_w_hh = (const float*)d_in[7];
  const float* i_b    = (const float*)d_in[8];
  const float* c_w_xh = (const float*)d_in[9];
  const float* c_w_hh = (const float*)d_in[10];
  const float* c_b    = (const float*)d_in[11];
  const float* o_w_xh = (const float*)d_in[12];
  const float* o_w_hh = (const float*)d_in[13];
  const float* o_b    = (const float*)d_in[14];
  const float* y_w_ho = (const float*)d_in[15];
  const float* y_b_o  = (const float*)d_in[16];

  char* ws = (char*)d_ws;
  unsigned short* Wcat = (unsigned short*)ws;                         // 8 MB
  unsigned short* ywT  = (unsigned short*)(ws + (size_t)(8u << 20));  // 8 MB
  unsigned short* Hbuf = (unsigned short*)(ws + (size_t)(16u << 20)); // 257*65536*2 B
  float* Cbuf = (float*)(ws + (size_t)(16u << 20) + (size_t)257 * 65536 * 2);
  const size_t needed = (size_t)(16u << 20) + (size_t)257 * 65536 * 2 + (size_t)65536 * 4;
  if (ws_size < needed) return;  // workspace too small: fail visibly

  const dim3 thr(256);
  hipLaunchKernelGGL(transpose_bf16_kernel, dim3(16, 16), thr, 0, stream, f_w_hh, 1024, Wcat, 4, 0);
  hipLaunchKernelGGL(transpose_bf16_kernel, dim3(16, 16), thr, 0, stream, i_w_hh, 1024, Wcat, 4, 1);
  hipLaunchKernelGGL(transpose_bf16_kernel, dim3(16, 16), thr, 0, stream, c_w_hh, 1024, Wcat, 4, 2);
  hipLaunchKernelGGL(transpose_bf16_kernel, dim3(16, 16), thr, 0, stream, o_w_hh, 1024, Wcat, 4, 3);
  hipLaunchKernelGGL(transpose_bf16_kernel, dim3(16, 64), thr, 0, stream, y_w_ho, 4096, ywT, 1, 0);
  hipLaunchKernelGGL(init_kernel, dim3(256), thr, 0, stream, H0, C0, Hbuf, Cbuf);

  for (int t = 0; t < T_; ++t) {
    hipLaunchKernelGGL(lstm_step_kernel, dim3(64), thr, 0, stream,
                       Wcat,
                       Hbuf + (size_t)t * 65536,
                       Hbuf + (size_t)(t + 1) * 65536,
                       Cbuf,
                       f_w_xh, i_w_xh, c_w_xh, o_w_xh,
                       f_b, i_b, c_b, o_b,
                       tokens, t);
  }

  hipLaunchKernelGGL(out_gemm_kernel, dim3(4096), thr, 0, stream,
                     Hbuf + 65536, ywT, y_b_o, (float*)d_out);

  float* outH = (float*)d_out + (size_t)T_ * B_ * V_;
  hipLaunchKernelGGL(final_kernel, dim3(256), thr, 0, stream,
                     Hbuf + (size_t)T_ * 65536, Cbuf, outH, outH + 65536);
}

// Round 2
// 4001.292 us; speedup vs baseline: 1.4237x; 1.4237x over previous
//
#include <hip/hip_runtime.h>
#include <stdint.h>
#include <stddef.h>

// LSTM: B=64, H=1024, V=4096, T=256
// Phase 0: transpose weights to bf16 k-contiguous layouts (Wcat c=h*4+g, ywT).
// Phase 1: ONE persistent kernel, 128 WGs x 256 thr, runs all 256 steps with a
//          hand-rolled grid barrier. W-slice resident in LDS; H streamed via
//          3-buf LDS ring with counted vmcnt; C in registers for all steps.
// Phase 2: one big 16384x4096x1024 bf16 GEMM for Y.
// Workspace: WcatT 8MB | ywT 8MB | Hbuf (257*64*1024 bf16) 33.7MB | cnt 128B

#define B_ 64
#define H_ 1024
#define V_ 4096
#define T_ 256
#define NWG 128

typedef __attribute__((ext_vector_type(8))) short short8;
typedef __attribute__((ext_vector_type(4))) float f32x4;
typedef __attribute__((ext_vector_type(4))) float float4_;

static __device__ __forceinline__ unsigned short f2bf(float f) {
  union { float f; unsigned int u; } v; v.f = f;
  unsigned int u = v.u;
  unsigned int r = (u + 0x7fffu + ((u >> 16) & 1u)) >> 16;   // round-to-nearest-even
  return (unsigned short)r;
}
static __device__ __forceinline__ float bf2f(unsigned short s) {
  union { unsigned int u; float f; } v; v.u = ((unsigned int)s) << 16;
  return v.f;
}

static __device__ __forceinline__ void gload_lds16(const void* g, void* l) {
  // async global->LDS, 16B per lane; LDS dest = wave-uniform base + lane*16
  __builtin_amdgcn_global_load_lds((const __attribute__((address_space(1))) unsigned int*)g,
                                   (__attribute__((address_space(3))) unsigned int*)l,
                                   16, 0, 0);
}

// ---------------------------------------------------------------------------
// Tiled transpose fp32 (K x C) -> bf16 rows: dst[c = col*c_mul + c_add][k]
// grid: (K/64, C/64), 256 threads
// ---------------------------------------------------------------------------
__global__ void transpose_bf16_kernel(const float* __restrict__ src, int src_cols,
                                      unsigned short* __restrict__ dst,
                                      int c_mul, int c_add) {
  __shared__ float tile[64][65];
  const int k0 = blockIdx.x * 64, h0 = blockIdx.y * 64;
  const int t = threadIdx.x;
  {
    const int kk = t >> 2, seg = (t & 3) * 16;
    const float* s = src + (size_t)(k0 + kk) * src_cols + h0 + seg;
#pragma unroll
    for (int j = 0; j < 16; j += 4) {
      float4_ v = *(const float4_*)(s + j);
      tile[kk][seg + j + 0] = v[0];
      tile[kk][seg + j + 1] = v[1];
      tile[kk][seg + j + 2] = v[2];
      tile[kk][seg + j + 3] = v[3];
    }
  }
  __syncthreads();
  {
    const int hh = t >> 2, ks = (t & 3) * 16;
    const int c = (h0 + hh) * c_mul + c_add;
    short8 p0, p1;
#pragma unroll
    for (int j = 0; j < 8; ++j) {
      p0[j] = (short)f2bf(tile[ks + j][hh]);
      p1[j] = (short)f2bf(tile[ks + 8 + j][hh]);
    }
    unsigned short* d = dst + (size_t)c * 1024 + k0 + ks;
    *(short8*)(d) = p0;
    *(short8*)(d + 8) = p1;
  }
}

// ---------------------------------------------------------------------------
__global__ void init_kernel(const float* __restrict__ H0,
                            unsigned short* __restrict__ Hbuf0,
                            unsigned int* __restrict__ cnt) {
  const int i = blockIdx.x * 256 + threadIdx.x;  // 65536
  Hbuf0[i] = f2bf(H0[i]);
  if (i == 0) __hip_atomic_store(cnt, 0u, __ATOMIC_RELAXED, __HIP_MEMORY_SCOPE_AGENT);
}

// ---------------------------------------------------------------------------
// Persistent LSTM recurrence. 128 WGs x 256 thr (4 waves), 1 WG/CU.
// WG owns 32 gate-cols (c = h*4+g): W-slice 32x1024 bf16 = 64KB in LDS (once).
// Per step: A = Hin (64x1024 bf16) streamed in 8 chunks of k128 (16KB) through
// a 3-buffer ring; waves k-split (wave w handles k-quarter of each chunk);
// 4-way cross-wave reduction via LDS scratch (reuses ring bufs 0,1);
// epilogue: gates -> C (registers) -> H (bf16 global). Grid barrier per step.
// LDS: W 64KB @0 | ring 3x16KB @65536 | scratch = ring bufs 0,1.
// ---------------------------------------------------------------------------
#define AOFF 65536
#define SCR  65536

__launch_bounds__(256, 1)
__global__ void lstm_persistent_kernel(
    const unsigned short* __restrict__ Wcat,   // [4096][1024] bf16
    unsigned short* __restrict__ Hbuf,         // [257][64][1024] bf16
    unsigned int* __restrict__ cnt,            // grid barrier counter
    const float* __restrict__ C0,              // [64][1024] f32
    const float* __restrict__ xwf, const float* __restrict__ xwi,
    const float* __restrict__ xwc, const float* __restrict__ xwo,
    const float* __restrict__ bfv, const float* __restrict__ biv,
    const float* __restrict__ bcv, const float* __restrict__ bov,
    const int* __restrict__ tokens,
    float* __restrict__ outH, float* __restrict__ outC) {
  __shared__ __align__(16) unsigned char lds[114688];
  const int tid = threadIdx.x;
  const int wave = tid >> 6, lane = tid & 63;
  const int l15 = lane & 15, l4 = lane >> 4;
  const int wgc0 = blockIdx.x * 32;

  auto xw_of = [&](int g) -> const float* {
    return g == 0 ? xwf : g == 1 ? xwi : g == 2 ? xwc : xwo;
  };
  auto b_of = [&](int g) -> const float* {
    return g == 0 ? bfv : g == 1 ? biv : g == 2 ? bcv : bov;
  };

  // ---- per-lane constants & persistent register state ----
  int hh[2], gg[2];
  float bias_v[2], Creg[2][4], xg[2][4];
#pragma unroll
  for (int ni = 0; ni < 2; ++ni) {
    const int col = wgc0 + ni * 16 + l15;
    hh[ni] = col >> 2; gg[ni] = col & 3;
    bias_v[ni] = b_of(gg[ni])[hh[ni]];
#pragma unroll
    for (int r = 0; r < 4; ++r)
      Creg[ni][r] = C0[(size_t)(wave * 16 + l4 * 4 + r) * 1024 + hh[ni]];
  }
  {
    int tk[4];
#pragma unroll
    for (int r = 0; r < 4; ++r) tk[r] = tokens[(wave * 16 + l4 * 4 + r) * T_ + 0];
#pragma unroll
    for (int ni = 0; ni < 2; ++ni)
#pragma unroll
      for (int r = 0; r < 4; ++r)
        xg[ni][r] = xw_of(gg[ni])[(size_t)tk[r] * 1024 + hh[ni]];
  }

  // ---- stage W-slice into LDS (once), pre-swizzled source ----
  {
    const char* Wb = (const char*)(Wcat + (size_t)wgc0 * 1024);
#pragma unroll
    for (int it = 0; it < 16; ++it) {
      const int D = it * 4096 + wave * 1024 + lane * 16;
      const int row = D >> 11, off = D & 2047;
      const int so = off ^ ((row & 7) << 4);
      gload_lds16(Wb + (size_t)row * 2048 + so, &lds[it * 4096 + wave * 1024]);
    }
  }

  auto stageA = [&](int buf, int c, const char* Hsrc) {
#pragma unroll
    for (int it = 0; it < 4; ++it) {
      const int D = it * 4096 + wave * 1024 + lane * 16;
      const int row = D >> 8, off = D & 255;
      const int so = off ^ ((row & 7) << 4);
      gload_lds16(Hsrc + (size_t)row * 2048 + c * 256 + so,
                  &lds[AOFF + buf * 16384 + it * 4096 + wave * 1024]);
    }
  };

  f32x4 acc[4][2];
  const f32x4 zz = {0.f, 0.f, 0.f, 0.f};

  // prologue A stages for t=0 (chunks 0,1 -> bufs 0,1)
  stageA(0, 0, (const char*)Hbuf);
  stageA(1, 1, (const char*)Hbuf);

  unsigned int target = NWG;

#pragma unroll 1
  for (int t = 0; t < T_; ++t) {
    const char* Hs = (const char*)(Hbuf + (size_t)t * 65536);
#pragma unroll
    for (int mi = 0; mi < 4; ++mi)
#pragma unroll
      for (int ni = 0; ni < 2; ++ni) acc[mi][ni] = zz;

    // ---- K loop: 8 chunks of k128, counted-vmcnt ring, raw barriers ----
#pragma unroll
    for (int c = 0; c < 8; ++c) {
      if (c == 7) asm volatile("s_waitcnt vmcnt(0)" ::: "memory");
      else        asm volatile("s_waitcnt vmcnt(4)" ::: "memory");
      __builtin_amdgcn_sched_barrier(0);
      __builtin_amdgcn_s_barrier();
      __builtin_amdgcn_sched_barrier(0);
      if (c < 6) stageA((c + 2) % 3, c + 2, Hs);
      // compute on chunk c (buf c%3); wave handles k-slice wave*32 of chunk
      {
        const int abase = AOFF + (c % 3) * 16384;
        short8 a[4], b[2];
#pragma unroll
        for (int mi = 0; mi < 4; ++mi) {
          const int row = mi * 16 + l15;
          const int off = (wave * 64 + l4 * 16) ^ ((row & 7) << 4);
          a[mi] = *(const short8*)&lds[abase + row * 256 + off];
        }
#pragma unroll
        for (int ni = 0; ni < 2; ++ni) {
          const int row = ni * 16 + l15;
          const int off = (c * 256 + wave * 64 + l4 * 16) ^ ((row & 7) << 4);
          b[ni] = *(const short8*)&lds[row * 2048 + off];
        }
#pragma unroll
        for (int mi = 0; mi < 4; ++mi)
#pragma unroll
          for (int ni = 0; ni < 2; ++ni)
            acc[mi][ni] = __builtin_amdgcn_mfma_f32_16x16x32_bf16(a[mi], b[ni], acc[mi][ni], 0, 0, 0);
      }
      __builtin_amdgcn_sched_barrier(0);
    }

    // ---- cross-wave k-reduction via LDS scratch (ring bufs 0,1) ----
#pragma unroll
    for (int mi = 0; mi < 4; ++mi)
#pragma unroll
      for (int ni = 0; ni < 2; ++ni)
        *(f32x4*)&lds[SCR + wave * 8192 + (mi * 2 + ni) * 1024 + lane * 16] = acc[mi][ni];
    __syncthreads();

    int tok2[4];
    if (t < T_ - 1) {
#pragma unroll
      for (int r = 0; r < 4; ++r)
        tok2[r] = tokens[(wave * 16 + l4 * 4 + r) * T_ + (t + 1)];
    }

    f32x4 red[2];
#pragma unroll
    for (int ni = 0; ni < 2; ++ni) {
      red[ni] = zz;
#pragma unroll
      for (int s = 0; s < 4; ++s)
        red[ni] += *(const f32x4*)&lds[SCR + s * 8192 + (wave * 2 + ni) * 1024 + lane * 16];
    }

    // ---- epilogue: gates, C update (regs), H write ----
    unsigned short* Hout = Hbuf + (size_t)(t + 1) * 65536;
#pragma unroll
    for (int ni = 0; ni < 2; ++ni) {
#pragma unroll
      for (int r = 0; r < 4; ++r) {
        const float pre = red[ni][r] + xg[ni][r] + bias_v[ni];
        const float p1 = __shfl_down(pre, 1);
        const float p2 = __shfl_down(pre, 2);
        const float p3 = __shfl_down(pre, 3);
        if ((lane & 3) == 0) {
          const float pf = 1.f / (1.f + __expf(-pre));
          const float pi = 1.f / (1.f + __expf(-p1));
          const float e2 = __expf(2.f * p2);
          const float pc = (e2 - 1.f) / (e2 + 1.f);
          const float po = 1.f / (1.f + __expf(-p3));
          const float cn = pf * Creg[ni][r] + pi * pc;
          Creg[ni][r] = cn;
          const float hv = po * cn;
          const size_t idx = (size_t)(wave * 16 + l4 * 4 + r) * 1024 + hh[ni];
          Hout[idx] = f2bf(hv);
          if (t == T_ - 1) { outH[idx] = hv; outC[idx] = cn; }
        }
      }
    }

    if (t < T_ - 1) {
      // prefetch next-step x-gather (hidden under epilogue/sync)
#pragma unroll
      for (int ni = 0; ni < 2; ++ni)
#pragma unroll
        for (int r = 0; r < 4; ++r)
          xg[ni][r] = xw_of(gg[ni])[(size_t)tok2[r] * 1024 + hh[ni]];

      // ---- grid barrier (agent-scope release/acquire) ----
      __syncthreads();
      if (tid == 0) {
        __threadfence();
        __hip_atomic_fetch_add(cnt, 1u, __ATOMIC_ACQ_REL, __HIP_MEMORY_SCOPE_AGENT);
        while (__hip_atomic_load(cnt, __ATOMIC_ACQUIRE, __HIP_MEMORY_SCOPE_AGENT) < target) {}
        __threadfence();
      }
      __syncthreads();
      target += NWG;

      // prologue stages for t+1
      const char* Hn = (const char*)(Hbuf + (size_t)(t + 1) * 65536);
      stageA(0, 0, Hn);
      stageA(1, 1, Hn);
    }
  }
}

// ---------------------------------------------------------------------------
// Y = Hseq(16384x1024 bf16) @ ywT^T + bias -> fp32. m97-style 128x128, BK=32.
// grid: 4096 WGs (tm = id>>5, tn = id&31), 256 thr, waves 2x2, wave tile 64x64.
// ---------------------------------------------------------------------------
__launch_bounds__(256, 1)
__global__ void out_gemm_kernel(const unsigned short* __restrict__ A,   // [16384][1024] bf16
                                const unsigned short* __restrict__ Bw,  // ywT [4096][1024] bf16
                                const float* __restrict__ bias,         // [4096]
                                float* __restrict__ Yout) {             // [16384][4096] f32
  __shared__ unsigned char Ash[2][8192];   // 128 rows x 64B, XOR-swizzled
  __shared__ unsigned char Bsh[2][8192];
  const int tid = threadIdx.x;
  const int wave = tid >> 6, lane = tid & 63;
  const int wm = wave >> 1, wn = wave & 1;
  const int bid = blockIdx.x;
  const int tn = bid & 31, tm = bid >> 5;

  const char* Agb = (const char*)(A + (size_t)tm * 128 * 1024);
  const char* Bgb = (const char*)(Bw + (size_t)tn * 128 * 1024);

  f32x4 acc[4][4];
  const f32x4 zz = {0.f, 0.f, 0.f, 0.f};
#pragma unroll
  for (int mi = 0; mi < 4; ++mi)
#pragma unroll
    for (int ni = 0; ni < 4; ++ni) acc[mi][ni] = zz;

  auto stage = [&](int buf, int kc) {
#pragma unroll
    for (int j = 0; j < 2; ++j) {
      const int wbase = wave * 2048 + j * 1024;
      const int D = wbase + lane * 16;
      const int row = D >> 6, off = D & 63;
      const int so = off ^ ((row & 3) << 4);
      gload_lds16(Agb + (size_t)row * 2048 + kc * 64 + so, &Ash[buf][wbase]);
      gload_lds16(Bgb + (size_t)row * 2048 + kc * 64 + so, &Bsh[buf][wbase]);
    }
  };

  stage(0, 0);
  __syncthreads();

#pragma unroll 1
  for (int kc = 0; kc < 32; ++kc) {
    const int cur = kc & 1;
    if (kc < 31) stage(cur ^ 1, kc + 1);
    short8 a[4], b[4];
#pragma unroll
    for (int mi = 0; mi < 4; ++mi) {
      const int row = wm * 64 + mi * 16 + (lane & 15);
      const int off = ((lane >> 4) * 16) ^ ((row & 3) << 4);
      a[mi] = *(const short8*)&Ash[cur][row * 64 + off];
    }
#pragma unroll
    for (int ni = 0; ni < 4; ++ni) {
      const int row = wn * 64 + ni * 16 + (lane & 15);
      const int off = ((lane >> 4) * 16) ^ ((row & 3) << 4);
      b[ni] = *(const short8*)&Bsh[cur][row * 64 + off];
    }
#pragma unroll
    for (int mi = 0; mi < 4; ++mi)
#pragma unroll
      for (int ni = 0; ni < 4; ++ni)
        acc[mi][ni] = __builtin_amdgcn_mfma_f32_16x16x32_bf16(a[mi], b[ni], acc[mi][ni], 0, 0, 0);
    __syncthreads();
  }

  const int l15 = lane & 15, l4 = lane >> 4;
#pragma unroll
  for (int ni = 0; ni < 4; ++ni) {
    const int n = tn * 128 + wn * 64 + ni * 16 + l15;
    const float bv = bias[n];
#pragma unroll
    for (int mi = 0; mi < 4; ++mi) {
#pragma unroll
      for (int r = 0; r < 4; ++r) {
        const int m = tm * 128 + wm * 64 + mi * 16 + l4 * 4 + r;
        Yout[(size_t)m * 4096 + n] = acc[mi][ni][r] + bv;
      }
    }
  }
}

// ---------------------------------------------------------------------------
extern "C" void kernel_launch(void* const* d_in, const int* in_sizes, int n_in,
                              void* d_out, int out_size, void* d_ws, size_t ws_size,
                              hipStream_t stream) {
  const int* tokens   = (const int*)d_in[0];
  const float* H0     = (const float*)d_in[1];
  const float* C0     = (const float*)d_in[2];
  const float* f_w_xh = (const float*)d_in[3];
  const float* f_w_hh = (const float*)d_in[4];
  const float* f_b    = (const float*)d_in[5];
  const float* i_w_xh = (const float*)d_in[6];
  const float* i_w_hh = (const float*)d_in[7];
  const float* i_b    = (const float*)d_in[8];
  const float* c_w_xh = (const float*)d_in[9];
  const float* c_w_hh = (const float*)d_in[10];
  const float* c_b    = (const float*)d_in[11];
  const float* o_w_xh = (const float*)d_in[12];
  const float* o_w_hh = (const float*)d_in[13];
  const float* o_b    = (const float*)d_in[14];
  const float* y_w_ho = (const float*)d_in[15];
  const float* y_b_o  = (const float*)d_in[16];

  char* ws = (char*)d_ws;
  unsigned short* Wcat = (unsigned short*)ws;                         // 8 MB
  unsigned short* ywT  = (unsigned short*)(ws + (size_t)(8u << 20));  // 8 MB
  unsigned short* Hbuf = (unsigned short*)(ws + (size_t)(16u << 20)); // 257*65536*2 B
  unsigned int* cnt = (unsigned int*)(ws + (size_t)(16u << 20) + (size_t)257 * 65536 * 2);
  const size_t needed = (size_t)(16u << 20) + (size_t)257 * 65536 * 2 + 256;
  if (ws_size < needed) return;  // workspace too small: fail visibly

  const dim3 thr(256);
  hipLaunchKernelGGL(transpose_bf16_kernel, dim3(16, 16), thr, 0, stream, f_w_hh, 1024, Wcat, 4, 0);
  hipLaunchKernelGGL(transpose_bf16_kernel, dim3(16, 16), thr, 0, stream, i_w_hh, 1024, Wcat, 4, 1);
  hipLaunchKernelGGL(transpose_bf16_kernel, dim3(16, 16), thr, 0, stream, c_w_hh, 1024, Wcat, 4, 2);
  hipLaunchKernelGGL(transpose_bf16_kernel, dim3(16, 16), thr, 0, stream, o_w_hh, 1024, Wcat, 4, 3);
  hipLaunchKernelGGL(transpose_bf16_kernel, dim3(16, 64), thr, 0, stream, y_w_ho, 4096, ywT, 1, 0);
  hipLaunchKernelGGL(init_kernel, dim3(256), thr, 0, stream, H0, Hbuf, cnt);

  float* outH = (float*)d_out + (size_t)T_ * B_ * V_;
  hipLaunchKernelGGL(lstm_persistent_kernel, dim3(NWG), thr, 0, stream,
                     Wcat, Hbuf, cnt, C0,
                     f_w_xh, i_w_xh, c_w_xh, o_w_xh,
                     f_b, i_b, c_b, o_b,
                     tokens, outH, outH + 65536);

  hipLaunchKernelGGL(out_gemm_kernel, dim3(4096), thr, 0, stream,
                     Hbuf + 65536, ywT, y_b_o, (float*)d_out);
}

// Round 3
// 2807.172 us; speedup vs baseline: 2.0294x; 1.4254x over previous
//
#include <hip/hip_runtime.h>
#include <stdint.h>
#include <stddef.h>

// LSTM: B=64, H=1024, V=4096, T=256
// Phase 0: transpose weights to bf16 k-contiguous layouts (Wcat c=h*4+g, ywT).
// Phase 1: ONE persistent kernel, 128 WGs x 256 thr, all 256 steps.
//   - W-slice (32 gate-cols, 64KB) resident in LDS for the whole kernel
//   - H streamed per step via 4-buf LDS ring, counted vmcnt(8), raw s_barrier
//   - waves m-split (wave owns 16 batch rows, full K) -> no cross-wave reduce
//   - C in registers all 256 steps
//   - grid barrier: 2-level counters, RELAXED polls, single ACQUIRE on exit
// Phase 2: one big 16384x4096x1024 bf16 GEMM for Y.
// Workspace: WcatT 8MB | ywT 8MB | Hbuf (257*64*1024 bf16) 33.7MB | cnt 1KB

#define B_ 64
#define H_ 1024
#define V_ 4096
#define T_ 256
#define NWG 128

typedef __attribute__((ext_vector_type(8))) short short8;
typedef __attribute__((ext_vector_type(4))) float f32x4;
typedef __attribute__((ext_vector_type(4))) float float4_;

static __device__ __forceinline__ unsigned short f2bf(float f) {
  union { float f; unsigned int u; } v; v.f = f;
  unsigned int u = v.u;
  unsigned int r = (u + 0x7fffu + ((u >> 16) & 1u)) >> 16;   // round-to-nearest-even
  return (unsigned short)r;
}

static __device__ __forceinline__ void gload_lds16(const void* g, void* l) {
  // async global->LDS, 16B per lane; LDS dest = wave-uniform base + lane*16
  __builtin_amdgcn_global_load_lds((const __attribute__((address_space(1))) unsigned int*)g,
                                   (__attribute__((address_space(3))) unsigned int*)l,
                                   16, 0, 0);
}

// ---------------------------------------------------------------------------
// Tiled transpose fp32 (K x C) -> bf16 rows: dst[c = col*c_mul + c_add][k]
// grid: (K/64, C/64), 256 threads
// ---------------------------------------------------------------------------
__global__ void transpose_bf16_kernel(const float* __restrict__ src, int src_cols,
                                      unsigned short* __restrict__ dst,
                                      int c_mul, int c_add) {
  __shared__ float tile[64][65];
  const int k0 = blockIdx.x * 64, h0 = blockIdx.y * 64;
  const int t = threadIdx.x;
  {
    const int kk = t >> 2, seg = (t & 3) * 16;
    const float* s = src + (size_t)(k0 + kk) * src_cols + h0 + seg;
#pragma unroll
    for (int j = 0; j < 16; j += 4) {
      float4_ v = *(const float4_*)(s + j);
      tile[kk][seg + j + 0] = v[0];
      tile[kk][seg + j + 1] = v[1];
      tile[kk][seg + j + 2] = v[2];
      tile[kk][seg + j + 3] = v[3];
    }
  }
  __syncthreads();
  {
    const int hh = t >> 2, ks = (t & 3) * 16;
    const int c = (h0 + hh) * c_mul + c_add;
    short8 p0, p1;
#pragma unroll
    for (int j = 0; j < 8; ++j) {
      p0[j] = (short)f2bf(tile[ks + j][hh]);
      p1[j] = (short)f2bf(tile[ks + 8 + j][hh]);
    }
    unsigned short* d = dst + (size_t)c * 1024 + k0 + ks;
    *(short8*)(d) = p0;
    *(short8*)(d + 8) = p1;
  }
}

// ---------------------------------------------------------------------------
__global__ void init_kernel(const float* __restrict__ H0,
                            unsigned short* __restrict__ Hbuf0,
                            unsigned int* __restrict__ cnt) {
  const int i = blockIdx.x * 256 + threadIdx.x;  // 65536
  Hbuf0[i] = f2bf(H0[i]);
  if (blockIdx.x == 0) cnt[threadIdx.x] = 0;     // zero barrier counters each launch
}

// ---------------------------------------------------------------------------
// Persistent LSTM recurrence. 128 WGs x 256 thr (4 waves).
// WG owns 32 gate-cols (c = h*4+g): W-slice 32x1024 bf16 = 64KB in LDS (once).
// Per step: A = Hin (64x1024 bf16) streamed in 8 chunks of k128 (16KB) through
// a 4-buffer ring (3 chunks in flight, vmcnt(8)). Wave w computes batch rows
// [16w,16w+16) x all 32 cols over full K (no cross-wave reduction).
// LDS: W 64KB @0 | ring 4x16KB @65536 = 128KB.
// ---------------------------------------------------------------------------
#define AOFF 65536

__launch_bounds__(256, 1)
__global__ void lstm_persistent_kernel(
    const unsigned short* __restrict__ Wcat,   // [4096][1024] bf16
    unsigned short* __restrict__ Hbuf,         // [257][64][1024] bf16
    unsigned int* __restrict__ cnt,            // [0]=root, [16*(g+1)]=group g
    const float* __restrict__ C0,              // [64][1024] f32
    const float* __restrict__ xwf, const float* __restrict__ xwi,
    const float* __restrict__ xwc, const float* __restrict__ xwo,
    const float* __restrict__ bfv, const float* __restrict__ biv,
    const float* __restrict__ bcv, const float* __restrict__ bov,
    const int* __restrict__ tokens,
    float* __restrict__ outH, float* __restrict__ outC) {
  __shared__ __align__(16) unsigned char lds[131072];
  const int tid = threadIdx.x;
  const int wave = tid >> 6, lane = tid & 63;
  const int l15 = lane & 15, l4 = lane >> 4;
  const int wgc0 = blockIdx.x * 32;

  auto xw_of = [&](int g) -> const float* {
    return g == 0 ? xwf : g == 1 ? xwi : g == 2 ? xwc : xwo;
  };
  auto b_of = [&](int g) -> const float* {
    return g == 0 ? bfv : g == 1 ? biv : g == 2 ? bcv : bov;
  };

  // ---- per-lane constants & persistent register state ----
  // output tile element: row(batch) = wave*16 + l4*4 + r, col = wgc0 + ni*16 + l15
  int hh[2], gg[2];
  float bias_v[2], Creg[2][4], xg[2][4];
#pragma unroll
  for (int ni = 0; ni < 2; ++ni) {
    const int col = wgc0 + ni * 16 + l15;
    hh[ni] = col >> 2; gg[ni] = col & 3;
    bias_v[ni] = b_of(gg[ni])[hh[ni]];
#pragma unroll
    for (int r = 0; r < 4; ++r)
      Creg[ni][r] = C0[(size_t)(wave * 16 + l4 * 4 + r) * 1024 + hh[ni]];
  }
  {
    int tk[4];
#pragma unroll
    for (int r = 0; r < 4; ++r) tk[r] = tokens[(wave * 16 + l4 * 4 + r) * T_ + 0];
#pragma unroll
    for (int ni = 0; ni < 2; ++ni)
#pragma unroll
      for (int r = 0; r < 4; ++r)
        xg[ni][r] = xw_of(gg[ni])[(size_t)tk[r] * 1024 + hh[ni]];
  }

  // ---- stage W-slice into LDS (once), pre-swizzled source ----
  {
    const char* Wb = (const char*)(Wcat + (size_t)wgc0 * 1024);
#pragma unroll
    for (int it = 0; it < 16; ++it) {
      const int D = it * 4096 + wave * 1024 + lane * 16;
      const int row = D >> 11, off = D & 2047;
      const int so = off ^ ((row & 7) << 4);
      gload_lds16(Wb + (size_t)row * 2048 + so, &lds[it * 4096 + wave * 1024]);
    }
  }

  auto stageA = [&](int buf, int c, const char* Hsrc) {
#pragma unroll
    for (int it = 0; it < 4; ++it) {
      const int D = it * 4096 + wave * 1024 + lane * 16;
      const int row = D >> 8, off = D & 255;
      const int so = off ^ ((row & 7) << 4);
      gload_lds16(Hsrc + (size_t)row * 2048 + c * 256 + so,
                  &lds[AOFF + buf * 16384 + it * 4096 + wave * 1024]);
    }
  };

  f32x4 acc[2];
  const f32x4 zz = {0.f, 0.f, 0.f, 0.f};

  // prologue A stages for t=0 (chunks 0,1,2 -> bufs 0,1,2)
  stageA(0, 0, (const char*)Hbuf);
  stageA(1, 1, (const char*)Hbuf);
  stageA(2, 2, (const char*)Hbuf);

  unsigned int rtarget = 8;
  const unsigned int grp = blockIdx.x & 7;
  unsigned int* gcnt = cnt + 16 * (grp + 1);

#pragma unroll 1
  for (int t = 0; t < T_; ++t) {
    const char* Hs = (const char*)(Hbuf + (size_t)t * 65536);
    acc[0] = zz; acc[1] = zz;

    // ---- K loop: 8 chunks of k128, ring-4, counted vmcnt, raw barriers ----
#pragma unroll
    for (int c = 0; c < 8; ++c) {
      if (c <= 5)      asm volatile("s_waitcnt vmcnt(8)" ::: "memory");
      else if (c == 6) asm volatile("s_waitcnt vmcnt(4)" ::: "memory");
      else             asm volatile("s_waitcnt vmcnt(0)" ::: "memory");
      __builtin_amdgcn_sched_barrier(0);
      __builtin_amdgcn_s_barrier();
      __builtin_amdgcn_sched_barrier(0);
      if (c < 5) stageA((c + 3) & 3, c + 3, Hs);
      // compute chunk c from buf c&3: rows wave*16.., cols 0..31, k = c*128..+128
      {
        const int abase = AOFF + (c & 3) * 16384;
        const int arow = wave * 16 + l15;
        const int abyte = abase + arow * 256;
        const int aswz = (arow & 7) << 4;
        const int bswz = (l15 & 7) << 4;
#pragma unroll
        for (int ks = 0; ks < 4; ++ks) {
          const int koff = ks * 64 + l4 * 16;
          short8 a  = *(const short8*)&lds[abyte + (koff ^ aswz)];
          short8 b0 = *(const short8*)&lds[(size_t)l15 * 2048 + ((c * 256 + koff) ^ bswz)];
          short8 b1 = *(const short8*)&lds[(size_t)(16 + l15) * 2048 + ((c * 256 + koff) ^ bswz)];
          acc[0] = __builtin_amdgcn_mfma_f32_16x16x32_bf16(a, b0, acc[0], 0, 0, 0);
          acc[1] = __builtin_amdgcn_mfma_f32_16x16x32_bf16(a, b1, acc[1], 0, 0, 0);
        }
      }
      __builtin_amdgcn_sched_barrier(0);
    }

    // next-step token loads (issue early, consumed after epilogue)
    int tok2[4];
    if (t < T_ - 1) {
#pragma unroll
      for (int r = 0; r < 4; ++r)
        tok2[r] = tokens[(wave * 16 + l4 * 4 + r) * T_ + (t + 1)];
    }

    // ---- epilogue: gates, C update (regs), H write ----
    unsigned short* Hout = Hbuf + (size_t)(t + 1) * 65536;
#pragma unroll
    for (int ni = 0; ni < 2; ++ni) {
#pragma unroll
      for (int r = 0; r < 4; ++r) {
        const float pre = acc[ni][r] + xg[ni][r] + bias_v[ni];
        const float p1 = __shfl_down(pre, 1);
        const float p2 = __shfl_down(pre, 2);
        const float p3 = __shfl_down(pre, 3);
        if ((lane & 3) == 0) {
          const float pf = 1.f / (1.f + __expf(-pre));
          const float pi = 1.f / (1.f + __expf(-p1));
          const float e2 = __expf(2.f * p2);
          const float pc = (e2 - 1.f) / (e2 + 1.f);
          const float po = 1.f / (1.f + __expf(-p3));
          const float cn = pf * Creg[ni][r] + pi * pc;
          Creg[ni][r] = cn;
          const float hv = po * cn;
          const size_t idx = (size_t)(wave * 16 + l4 * 4 + r) * 1024 + hh[ni];
          Hout[idx] = f2bf(hv);
          if (t == T_ - 1) { outH[idx] = hv; outC[idx] = cn; }
        }
      }
    }

    if (t < T_ - 1) {
      // prefetch next-step x-gather (hidden under the grid barrier)
#pragma unroll
      for (int ni = 0; ni < 2; ++ni)
#pragma unroll
        for (int r = 0; r < 4; ++r)
          xg[ni][r] = xw_of(gg[ni])[(size_t)tok2[r] * 1024 + hh[ni]];

      // ---- grid barrier: 2-level, relaxed polls, single acquire ----
      __syncthreads();
      if (tid == 0) {
        const unsigned int r =
            __hip_atomic_fetch_add(gcnt, 1u, __ATOMIC_ACQ_REL, __HIP_MEMORY_SCOPE_AGENT);
        if ((r & 15u) == 15u)
          __hip_atomic_fetch_add(cnt, 1u, __ATOMIC_RELEASE, __HIP_MEMORY_SCOPE_AGENT);
        while (__hip_atomic_load(cnt, __ATOMIC_RELAXED, __HIP_MEMORY_SCOPE_AGENT) < rtarget) {}
        (void)__hip_atomic_load(cnt, __ATOMIC_ACQUIRE, __HIP_MEMORY_SCOPE_AGENT);
      }
      __syncthreads();
      rtarget += 8;

      // prologue stages for t+1
      const char* Hn = (const char*)(Hbuf + (size_t)(t + 1) * 65536);
      stageA(0, 0, Hn);
      stageA(1, 1, Hn);
      stageA(2, 2, Hn);
    }
  }
}

// ---------------------------------------------------------------------------
// Y = Hseq(16384x1024 bf16) @ ywT^T + bias -> fp32. m97-style 128x128, BK=32.
// grid: 4096 WGs (tm = id>>5, tn = id&31), 256 thr, waves 2x2, wave tile 64x64.
// ---------------------------------------------------------------------------
__launch_bounds__(256, 1)
__global__ void out_gemm_kernel(const unsigned short* __restrict__ A,   // [16384][1024] bf16
                                const unsigned short* __restrict__ Bw,  // ywT [4096][1024] bf16
                                const float* __restrict__ bias,         // [4096]
                                float* __restrict__ Yout) {             // [16384][4096] f32
  __shared__ unsigned char Ash[2][8192];   // 128 rows x 64B, XOR-swizzled
  __shared__ unsigned char Bsh[2][8192];
  const int tid = threadIdx.x;
  const int wave = tid >> 6, lane = tid & 63;
  const int wm = wave >> 1, wn = wave & 1;
  const int bid = blockIdx.x;
  const int tn = bid & 31, tm = bid >> 5;

  const char* Agb = (const char*)(A + (size_t)tm * 128 * 1024);
  const char* Bgb = (const char*)(Bw + (size_t)tn * 128 * 1024);

  f32x4 acc[4][4];
  const f32x4 zz = {0.f, 0.f, 0.f, 0.f};
#pragma unroll
  for (int mi = 0; mi < 4; ++mi)
#pragma unroll
    for (int ni = 0; ni < 4; ++ni) acc[mi][ni] = zz;

  auto stage = [&](int buf, int kc) {
#pragma unroll
    for (int j = 0; j < 2; ++j) {
      const int wbase = wave * 2048 + j * 1024;
      const int D = wbase + lane * 16;
      const int row = D >> 6, off = D & 63;
      const int so = off ^ ((row & 3) << 4);
      gload_lds16(Agb + (size_t)row * 2048 + kc * 64 + so, &Ash[buf][wbase]);
      gload_lds16(Bgb + (size_t)row * 2048 + kc * 64 + so, &Bsh[buf][wbase]);
    }
  };

  stage(0, 0);
  __syncthreads();

#pragma unroll 1
  for (int kc = 0; kc < 32; ++kc) {
    const int cur = kc & 1;
    if (kc < 31) stage(cur ^ 1, kc + 1);
    short8 a[4], b[4];
#pragma unroll
    for (int mi = 0; mi < 4; ++mi) {
      const int row = wm * 64 + mi * 16 + (lane & 15);
      const int off = ((lane >> 4) * 16) ^ ((row & 3) << 4);
      a[mi] = *(const short8*)&Ash[cur][row * 64 + off];
    }
#pragma unroll
    for (int ni = 0; ni < 4; ++ni) {
      const int row = wn * 64 + ni * 16 + (lane & 15);
      const int off = ((lane >> 4) * 16) ^ ((row & 3) << 4);
      b[ni] = *(const short8*)&Bsh[cur][row * 64 + off];
    }
#pragma unroll
    for (int mi = 0; mi < 4; ++mi)
#pragma unroll
      for (int ni = 0; ni < 4; ++ni)
        acc[mi][ni] = __builtin_amdgcn_mfma_f32_16x16x32_bf16(a[mi], b[ni], acc[mi][ni], 0, 0, 0);
    __syncthreads();
  }

  const int l15 = lane & 15, l4 = lane >> 4;
#pragma unroll
  for (int ni = 0; ni < 4; ++ni) {
    const int n = tn * 128 + wn * 64 + ni * 16 + l15;
    const float bv = bias[n];
#pragma unroll
    for (int mi = 0; mi < 4; ++mi) {
#pragma unroll
      for (int r = 0; r < 4; ++r) {
        const int m = tm * 128 + wm * 64 + mi * 16 + l4 * 4 + r;
        Yout[(size_t)m * 4096 + n] = acc[mi][ni][r] + bv;
      }
    }
  }
}

// ---------------------------------------------------------------------------
extern "C" void kernel_launch(void* const* d_in, const int* in_sizes, int n_in,
                              void* d_out, int out_size, void* d_ws, size_t ws_size,
                              hipStream_t stream) {
  const int* tokens   = (const int*)d_in[0];
  const float* H0     = (const float*)d_in[1];
  const float* C0     = (const float*)d_in[2];
  const float* f_w_xh = (const float*)d_in[3];
  const float* f_w_hh = (const float*)d_in[4];
  const float* f_b    = (const float*)d_in[5];
  const float* i_w_xh = (const float*)d_in[6];
  const float* i_w_hh = (const float*)d_in[7];
  const float* i_b    = (const float*)d_in[8];
  const float* c_w_xh = (const float*)d_in[9];
  const float* c_w_hh = (const float*)d_in[10];
  const float* c_b    = (const float*)d_in[11];
  const float* o_w_xh = (const float*)d_in[12];
  const float* o_w_hh = (const float*)d_in[13];
  const float* o_b    = (const float*)d_in[14];
  const float* y_w_ho = (const float*)d_in[15];
  const float* y_b_o  = (const float*)d_in[16];

  char* ws = (char*)d_ws;
  unsigned short* Wcat = (unsigned short*)ws;                         // 8 MB
  unsigned short* ywT  = (unsigned short*)(ws + (size_t)(8u << 20));  // 8 MB
  unsigned short* Hbuf = (unsigned short*)(ws + (size_t)(16u << 20)); // 257*65536*2 B
  unsigned int* cnt = (unsigned int*)(ws + (size_t)(16u << 20) + (size_t)257 * 65536 * 2);
  const size_t needed = (size_t)(16u << 20) + (size_t)257 * 65536 * 2 + 1024;
  if (ws_size < needed) return;  // workspace too small: fail visibly

  const dim3 thr(256);
  hipLaunchKernelGGL(transpose_bf16_kernel, dim3(16, 16), thr, 0, stream, f_w_hh, 1024, Wcat, 4, 0);
  hipLaunchKernelGGL(transpose_bf16_kernel, dim3(16, 16), thr, 0, stream, i_w_hh, 1024, Wcat, 4, 1);
  hipLaunchKernelGGL(transpose_bf16_kernel, dim3(16, 16), thr, 0, stream, c_w_hh, 1024, Wcat, 4, 2);
  hipLaunchKernelGGL(transpose_bf16_kernel, dim3(16, 16), thr, 0, stream, o_w_hh, 1024, Wcat, 4, 3);
  hipLaunchKernelGGL(transpose_bf16_kernel, dim3(16, 64), thr, 0, stream, y_w_ho, 4096, ywT, 1, 0);
  hipLaunchKernelGGL(init_kernel, dim3(256), thr, 0, stream, H0, Hbuf, cnt);

  float* outH = (float*)d_out + (size_t)T_ * B_ * V_;
  hipLaunchKernelGGL(lstm_persistent_kernel, dim3(NWG), thr, 0, stream,
                     Wcat, Hbuf, cnt, C0,
                     f_w_xh, i_w_xh, c_w_xh, o_w_xh,
                     f_b, i_b, c_b, o_b,
                     tokens, outH, outH + 65536);

  hipLaunchKernelGGL(out_gemm_kernel, dim3(4096), thr, 0, stream,
                     Hbuf + 65536, ywT, y_b_o, (float*)d_out);
}

// Round 4
// 2108.229 us; speedup vs baseline: 2.7022x; 1.3315x over previous
//
#include <hip/hip_runtime.h>
#include <stdint.h>
#include <stddef.h>

// LSTM: B=64, H=1024, V=4096, T=256
// Phase 0: transpose weights to bf16 k-contiguous layouts (Wcat c=h*4+g, ywT).
// Phase 1: ONE persistent kernel, 128 WGs x 256 thr, all 256 steps.
//   - W-slice (32 gate-cols, 64KB) resident in LDS for the whole kernel
//   - H is the ONLY producer-consumer data: all H loads/stores use sc0|sc1
//     (L2-bypass, coherent via Infinity Cache) -> NO buffer_inv / wbl2 ever
//   - grid barrier: 2-level counters, all-RELAXED atomics, vmcnt(0) ordering
//   - H streamed via 5-buf LDS ring, lead-4, counted vmcnt, raw s_barrier
//   - waves m-split (wave owns 16 batch rows, full K); C in registers
// Phase 2: one big 16384x4096x1024 bf16 GEMM for Y.
// Workspace: WcatT 8MB | ywT 8MB | Hbuf (257*64*1024 bf16) 33.7MB | cnt 1KB

#define B_ 64
#define H_ 1024
#define V_ 4096
#define T_ 256
#define NWG 128

typedef __attribute__((ext_vector_type(8))) short short8;
typedef __attribute__((ext_vector_type(4))) float f32x4;
typedef __attribute__((ext_vector_type(4))) float float4_;
typedef __attribute__((ext_vector_type(2))) unsigned int uint2v;

static __device__ __forceinline__ unsigned short f2bf(float f) {
  union { float f; unsigned int u; } v; v.f = f;
  unsigned int u = v.u;
  unsigned int r = (u + 0x7fffu + ((u >> 16) & 1u)) >> 16;   // round-to-nearest-even
  return (unsigned short)r;
}

static __device__ __forceinline__ void gload_lds16(const void* g, void* l) {
  // async global->LDS, 16B per lane; LDS dest = wave-uniform base + lane*16
  __builtin_amdgcn_global_load_lds((const __attribute__((address_space(1))) unsigned int*)g,
                                   (__attribute__((address_space(3))) unsigned int*)l,
                                   16, 0, 0);
}
static __device__ __forceinline__ void gload_lds16_sc(const void* g, void* l) {
  // same, with SC0|SC1 (CPol 0x11): bypass L2, read at device coherence point
  __builtin_amdgcn_global_load_lds((const __attribute__((address_space(1))) unsigned int*)g,
                                   (__attribute__((address_space(3))) unsigned int*)l,
                                   16, 0, 17);
}

// ---------------------------------------------------------------------------
// Tiled transpose fp32 (K x C) -> bf16 rows: dst[c = col*c_mul + c_add][k]
// grid: (K/64, C/64), 256 threads
// ---------------------------------------------------------------------------
__global__ void transpose_bf16_kernel(const float* __restrict__ src, int src_cols,
                                      unsigned short* __restrict__ dst,
                                      int c_mul, int c_add) {
  __shared__ float tile[64][65];
  const int k0 = blockIdx.x * 64, h0 = blockIdx.y * 64;
  const int t = threadIdx.x;
  {
    const int kk = t >> 2, seg = (t & 3) * 16;
    const float* s = src + (size_t)(k0 + kk) * src_cols + h0 + seg;
#pragma unroll
    for (int j = 0; j < 16; j += 4) {
      float4_ v = *(const float4_*)(s + j);
      tile[kk][seg + j + 0] = v[0];
      tile[kk][seg + j + 1] = v[1];
      tile[kk][seg + j + 2] = v[2];
      tile[kk][seg + j + 3] = v[3];
    }
  }
  __syncthreads();
  {
    const int hh = t >> 2, ks = (t & 3) * 16;
    const int c = (h0 + hh) * c_mul + c_add;
    short8 p0, p1;
#pragma unroll
    for (int j = 0; j < 8; ++j) {
      p0[j] = (short)f2bf(tile[ks + j][hh]);
      p1[j] = (short)f2bf(tile[ks + 8 + j][hh]);
    }
    unsigned short* d = dst + (size_t)c * 1024 + k0 + ks;
    *(short8*)(d) = p0;
    *(short8*)(d + 8) = p1;
  }
}

// ---------------------------------------------------------------------------
__global__ void init_kernel(const float* __restrict__ H0,
                            unsigned short* __restrict__ Hbuf0,
                            unsigned int* __restrict__ cnt) {
  const int i = blockIdx.x * 256 + threadIdx.x;  // 65536
  Hbuf0[i] = f2bf(H0[i]);
  if (blockIdx.x == 0) cnt[threadIdx.x] = 0;     // zero barrier counters each launch
}

// ---------------------------------------------------------------------------
// Persistent LSTM recurrence. 128 WGs x 256 thr (4 waves).
// LDS: W 64KB @0 | ring 5x16KB @65536 = 144KB.
// ---------------------------------------------------------------------------
#define AOFF 65536

__launch_bounds__(256, 1)
__global__ void lstm_persistent_kernel(
    const unsigned short* __restrict__ Wcat,   // [4096][1024] bf16
    unsigned short* __restrict__ Hbuf,         // [257][64][1024] bf16
    unsigned int* __restrict__ cnt,            // [0]=root, [16*(g+1)]=group g
    const float* __restrict__ C0,              // [64][1024] f32
    const float* __restrict__ xwf, const float* __restrict__ xwi,
    const float* __restrict__ xwc, const float* __restrict__ xwo,
    const float* __restrict__ bfv, const float* __restrict__ biv,
    const float* __restrict__ bcv, const float* __restrict__ bov,
    const int* __restrict__ tokens,
    float* __restrict__ outH, float* __restrict__ outC) {
  __shared__ __align__(16) unsigned char lds[147456];
  const int tid = threadIdx.x;
  const int wave = tid >> 6, lane = tid & 63;
  const int l15 = lane & 15, l4 = lane >> 4;
  const int wgc0 = blockIdx.x * 32;
  const int hbase0 = wgc0 >> 2;

  auto xw_of = [&](int g) -> const float* {
    return g == 0 ? xwf : g == 1 ? xwi : g == 2 ? xwc : xwo;
  };
  auto b_of = [&](int g) -> const float* {
    return g == 0 ? bfv : g == 1 ? biv : g == 2 ? bcv : bov;
  };

  // ---- per-lane constants & persistent register state ----
  // output tile element: row(batch) = wave*16 + l4*4 + r, col = wgc0 + ni*16 + l15
  int hh[2], gg[2];
  float bias_v[2], Creg[2][4], xg[2][4];
#pragma unroll
  for (int ni = 0; ni < 2; ++ni) {
    const int col = wgc0 + ni * 16 + l15;
    hh[ni] = col >> 2; gg[ni] = col & 3;
    bias_v[ni] = b_of(gg[ni])[hh[ni]];
#pragma unroll
    for (int r = 0; r < 4; ++r)
      Creg[ni][r] = C0[(size_t)(wave * 16 + l4 * 4 + r) * 1024 + hh[ni]];
  }
  {
    int tk[4];
#pragma unroll
    for (int r = 0; r < 4; ++r) tk[r] = tokens[(wave * 16 + l4 * 4 + r) * T_ + 0];
#pragma unroll
    for (int ni = 0; ni < 2; ++ni)
#pragma unroll
      for (int r = 0; r < 4; ++r)
        xg[ni][r] = xw_of(gg[ni])[(size_t)tk[r] * 1024 + hh[ni]];
  }

  // ---- stage W-slice into LDS (once), pre-swizzled source, cached load ----
  {
    const char* Wb = (const char*)(Wcat + (size_t)wgc0 * 1024);
#pragma unroll
    for (int it = 0; it < 16; ++it) {
      const int D = it * 4096 + wave * 1024 + lane * 16;
      const int row = D >> 11, off = D & 2047;
      const int so = off ^ ((row & 7) << 4);
      gload_lds16(Wb + (size_t)row * 2048 + so, &lds[it * 4096 + wave * 1024]);
    }
  }

  auto stageA = [&](int buf, int c, const char* Hsrc) {
#pragma unroll
    for (int it = 0; it < 4; ++it) {
      const int D = it * 4096 + wave * 1024 + lane * 16;
      const int row = D >> 8, off = D & 255;
      const int so = off ^ ((row & 7) << 4);
      gload_lds16_sc(Hsrc + (size_t)row * 2048 + c * 256 + so,
                     &lds[AOFF + buf * 16384 + it * 4096 + wave * 1024]);
    }
  };

  f32x4 acc[2];
  const f32x4 zz = {0.f, 0.f, 0.f, 0.f};

  // prologue A stages for t=0 (chunks 0..3 -> bufs 0..3)
  stageA(0, 0, (const char*)Hbuf);
  stageA(1, 1, (const char*)Hbuf);
  stageA(2, 2, (const char*)Hbuf);
  stageA(3, 3, (const char*)Hbuf);

  // one-time drain: clears constants/W/prologue so per-iter vmcnt counts hold
  asm volatile("s_waitcnt vmcnt(0)" ::: "memory");
  __syncthreads();

  unsigned int rtarget = 8;
  const unsigned int grp = blockIdx.x & 7;
  unsigned int* gcnt = cnt + 16 * (grp + 1);

#pragma unroll 1
  for (int t = 0; t < T_; ++t) {
    acc[0] = zz; acc[1] = zz;

    // next-step token loads: issued at step top -> covered by whole K loop.
    // FIFO-safe: vmcnt(12) waits below remain conservative with 4 extra loads.
    int tok2[4];
    if (t < T_ - 1) {
#pragma unroll
      for (int r = 0; r < 4; ++r)
        tok2[r] = tokens[(wave * 16 + l4 * 4 + r) * T_ + (t + 1)];
    }

    const char* Hs = (const char*)(Hbuf + (size_t)t * 65536);

    // ---- K loop: 8 chunks of k128, ring-5, lead-4, counted vmcnt ----
#pragma unroll
    for (int c = 0; c < 8; ++c) {
      if (c <= 4)      asm volatile("s_waitcnt vmcnt(12)" ::: "memory");
      else if (c == 5) asm volatile("s_waitcnt vmcnt(8)" ::: "memory");
      else if (c == 6) asm volatile("s_waitcnt vmcnt(4)" ::: "memory");
      else             asm volatile("s_waitcnt vmcnt(0)" ::: "memory");
      __builtin_amdgcn_sched_barrier(0);
      __builtin_amdgcn_s_barrier();
      __builtin_amdgcn_sched_barrier(0);
      if (c < 4) stageA((c + 4) % 5, c + 4, Hs);
      // compute chunk c from buf c%5: rows wave*16.., cols 0..31, k=c*128..+128
      {
        const int abase = AOFF + (c % 5) * 16384;
        const int arow = wave * 16 + l15;
        const int abyte = abase + arow * 256;
        const int aswz = (arow & 7) << 4;
        const int bswz = (l15 & 7) << 4;
#pragma unroll
        for (int ks = 0; ks < 4; ++ks) {
          const int koff = ks * 64 + l4 * 16;
          short8 a  = *(const short8*)&lds[abyte + (koff ^ aswz)];
          short8 b0 = *(const short8*)&lds[(size_t)l15 * 2048 + ((c * 256 + koff) ^ bswz)];
          short8 b1 = *(const short8*)&lds[(size_t)(16 + l15) * 2048 + ((c * 256 + koff) ^ bswz)];
          acc[0] = __builtin_amdgcn_mfma_f32_16x16x32_bf16(a, b0, acc[0], 0, 0, 0);
          acc[1] = __builtin_amdgcn_mfma_f32_16x16x32_bf16(a, b1, acc[1], 0, 0, 0);
        }
      }
      __builtin_amdgcn_sched_barrier(0);
    }

    // next-step x-gather prefetch into SEPARATE regs (epilogue covers latency)
    float xgn[2][4];
    if (t < T_ - 1) {
#pragma unroll
      for (int ni = 0; ni < 2; ++ni)
#pragma unroll
        for (int r = 0; r < 4; ++r)
          xgn[ni][r] = xw_of(gg[ni])[(size_t)tok2[r] * 1024 + hh[ni]];
    }

    // ---- epilogue: gates on all lanes, C in regs, packed sc0sc1 H store ----
    unsigned short* Hout = Hbuf + (size_t)(t + 1) * 65536;
#pragma unroll
    for (int ni = 0; ni < 2; ++ni) {
#pragma unroll
      for (int r = 0; r < 4; ++r) {
        const float pre = acc[ni][r] + xg[ni][r] + bias_v[ni];
        const float p1 = __shfl_down(pre, 1);
        const float p2 = __shfl_down(pre, 2);
        const float p3 = __shfl_down(pre, 3);
        const float pf = 1.f / (1.f + __expf(-pre));
        const float pi = 1.f / (1.f + __expf(-p1));
        const float e2 = __expf(2.f * p2);
        const float pc = (e2 - 1.f) / (e2 + 1.f);
        const float po = 1.f / (1.f + __expf(-p3));
        const float cn = pf * Creg[ni][r] + pi * pc;   // junk on lanes l15%4!=0: never stored
        Creg[ni][r] = cn;
        const float hv = po * cn;
        const unsigned int sbf = f2bf(hv);
        const unsigned int s4 = __shfl_down(sbf, 4);
        const unsigned int s8 = __shfl_down(sbf, 8);
        const unsigned int s12 = __shfl_down(sbf, 12);
        const int row = wave * 16 + l4 * 4 + r;
        if (l15 == 0) {
          uint2v dat; dat.x = sbf | (s4 << 16); dat.y = s8 | (s12 << 16);
          const unsigned long long addr =
              (unsigned long long)(Hout + (size_t)row * 1024 + hbase0 + ni * 4);
          asm volatile("global_store_dwordx2 %0, %1, off sc0 sc1"
                       :: "v"(addr), "v"(dat) : "memory");
        }
        if (t == T_ - 1 && (lane & 3) == 0) {
          const size_t idx = (size_t)row * 1024 + hh[ni];
          outH[idx] = hv; outC[idx] = cn;
        }
      }
    }

    if (t < T_ - 1) {
#pragma unroll
      for (int ni = 0; ni < 2; ++ni)
#pragma unroll
        for (int r = 0; r < 4; ++r) xg[ni][r] = xgn[ni][r];

      // ---- grid barrier: all-RELAXED, no cache maintenance ----
      asm volatile("s_waitcnt vmcnt(0)" ::: "memory");   // H stores + xgn drained
      __syncthreads();
      if (tid == 0) {
        const unsigned int r =
            __hip_atomic_fetch_add(gcnt, 1u, __ATOMIC_RELAXED, __HIP_MEMORY_SCOPE_AGENT);
        if ((r & 15u) == 15u)
          __hip_atomic_fetch_add(cnt, 1u, __ATOMIC_RELAXED, __HIP_MEMORY_SCOPE_AGENT);
        while (__hip_atomic_load(cnt, __ATOMIC_RELAXED, __HIP_MEMORY_SCOPE_AGENT) < rtarget) {}
      }
      __syncthreads();
      rtarget += 8;

      // prologue stages for t+1 (vmcnt baseline is 0 here)
      const char* Hn = (const char*)(Hbuf + (size_t)(t + 1) * 65536);
      stageA(0, 0, Hn);
      stageA(1, 1, Hn);
      stageA(2, 2, Hn);
      stageA(3, 3, Hn);
    }
  }
}

// ---------------------------------------------------------------------------
// Y = Hseq(16384x1024 bf16) @ ywT^T + bias -> fp32. m97-style 128x128, BK=32.
// grid: 4096 WGs (tm = id>>5, tn = id&31), 256 thr, waves 2x2, wave tile 64x64.
// ---------------------------------------------------------------------------
__launch_bounds__(256, 1)
__global__ void out_gemm_kernel(const unsigned short* __restrict__ A,   // [16384][1024] bf16
                                const unsigned short* __restrict__ Bw,  // ywT [4096][1024] bf16
                                const float* __restrict__ bias,         // [4096]
                                float* __restrict__ Yout) {             // [16384][4096] f32
  __shared__ unsigned char Ash[2][8192];   // 128 rows x 64B, XOR-swizzled
  __shared__ unsigned char Bsh[2][8192];
  const int tid = threadIdx.x;
  const int wave = tid >> 6, lane = tid & 63;
  const int wm = wave >> 1, wn = wave & 1;
  const int bid = blockIdx.x;
  const int tn = bid & 31, tm = bid >> 5;

  const char* Agb = (const char*)(A + (size_t)tm * 128 * 1024);
  const char* Bgb = (const char*)(Bw + (size_t)tn * 128 * 1024);

  f32x4 acc[4][4];
  const f32x4 zz = {0.f, 0.f, 0.f, 0.f};
#pragma unroll
  for (int mi = 0; mi < 4; ++mi)
#pragma unroll
    for (int ni = 0; ni < 4; ++ni) acc[mi][ni] = zz;

  auto stage = [&](int buf, int kc) {
#pragma unroll
    for (int j = 0; j < 2; ++j) {
      const int wbase = wave * 2048 + j * 1024;
      const int D = wbase + lane * 16;
      const int row = D >> 6, off = D & 63;
      const int so = off ^ ((row & 3) << 4);
      gload_lds16(Agb + (size_t)row * 2048 + kc * 64 + so, &Ash[buf][wbase]);
      gload_lds16(Bgb + (size_t)row * 2048 + kc * 64 + so, &Bsh[buf][wbase]);
    }
  };

  stage(0, 0);
  __syncthreads();

#pragma unroll 1
  for (int kc = 0; kc < 32; ++kc) {
    const int cur = kc & 1;
    if (kc < 31) stage(cur ^ 1, kc + 1);
    short8 a[4], b[4];
#pragma unroll
    for (int mi = 0; mi < 4; ++mi) {
      const int row = wm * 64 + mi * 16 + (lane & 15);
      const int off = ((lane >> 4) * 16) ^ ((row & 3) << 4);
      a[mi] = *(const short8*)&Ash[cur][row * 64 + off];
    }
#pragma unroll
    for (int ni = 0; ni < 4; ++ni) {
      const int row = wn * 64 + ni * 16 + (lane & 15);
      const int off = ((lane >> 4) * 16) ^ ((row & 3) << 4);
      b[ni] = *(const short8*)&Bsh[cur][row * 64 + off];
    }
#pragma unroll
    for (int mi = 0; mi < 4; ++mi)
#pragma unroll
      for (int ni = 0; ni < 4; ++ni)
        acc[mi][ni] = __builtin_amdgcn_mfma_f32_16x16x32_bf16(a[mi], b[ni], acc[mi][ni], 0, 0, 0);
    __syncthreads();
  }

  const int l15 = lane & 15, l4 = lane >> 4;
#pragma unroll
  for (int ni = 0; ni < 4; ++ni) {
    const int n = tn * 128 + wn * 64 + ni * 16 + l15;
    const float bv = bias[n];
#pragma unroll
    for (int mi = 0; mi < 4; ++mi) {
#pragma unroll
      for (int r = 0; r < 4; ++r) {
        const int m = tm * 128 + wm * 64 + mi * 16 + l4 * 4 + r;
        Yout[(size_t)m * 4096 + n] = acc[mi][ni][r] + bv;
      }
    }
  }
}

// ---------------------------------------------------------------------------
extern "C" void kernel_launch(void* const* d_in, const int* in_sizes, int n_in,
                              void* d_out, int out_size, void* d_ws, size_t ws_size,
                              hipStream_t stream) {
  const int* tokens   = (const int*)d_in[0];
  const float* H0     = (const float*)d_in[1];
  const float* C0     = (const float*)d_in[2];
  const float* f_w_xh = (const float*)d_in[3];
  const float* f_w_hh = (const float*)d_in[4];
  const float* f_b    = (const float*)d_in[5];
  const float* i_w_xh = (const float*)d_in[6];
  const float* i_w_hh = (const float*)d_in[7];
  const float* i_b    = (const float*)d_in[8];
  const float* c_w_xh = (const float*)d_in[9];
  const float* c_w_hh = (const float*)d_in[10];
  const float* c_b    = (const float*)d_in[11];
  const float* o_w_xh = (const float*)d_in[12];
  const float* o_w_hh = (const float*)d_in[13];
  const float* o_b    = (const float*)d_in[14];
  const float* y_w_ho = (const float*)d_in[15];
  const float* y_b_o  = (const float*)d_in[16];

  char* ws = (char*)d_ws;
  unsigned short* Wcat = (unsigned short*)ws;                         // 8 MB
  unsigned short* ywT  = (unsigned short*)(ws + (size_t)(8u << 20));  // 8 MB
  unsigned short* Hbuf = (unsigned short*)(ws + (size_t)(16u << 20)); // 257*65536*2 B
  unsigned int* cnt = (unsigned int*)(ws + (size_t)(16u << 20) + (size_t)257 * 65536 * 2);
  const size_t needed = (size_t)(16u << 20) + (size_t)257 * 65536 * 2 + 1024;
  if (ws_size < needed) return;  // workspace too small: fail visibly

  const dim3 thr(256);
  hipLaunchKernelGGL(transpose_bf16_kernel, dim3(16, 16), thr, 0, stream, f_w_hh, 1024, Wcat, 4, 0);
  hipLaunchKernelGGL(transpose_bf16_kernel, dim3(16, 16), thr, 0, stream, i_w_hh, 1024, Wcat, 4, 1);
  hipLaunchKernelGGL(transpose_bf16_kernel, dim3(16, 16), thr, 0, stream, c_w_hh, 1024, Wcat, 4, 2);
  hipLaunchKernelGGL(transpose_bf16_kernel, dim3(16, 16), thr, 0, stream, o_w_hh, 1024, Wcat, 4, 3);
  hipLaunchKernelGGL(transpose_bf16_kernel, dim3(16, 64), thr, 0, stream, y_w_ho, 4096, ywT, 1, 0);
  hipLaunchKernelGGL(init_kernel, dim3(256), thr, 0, stream, H0, Hbuf, cnt);

  float* outH = (float*)d_out + (size_t)T_ * B_ * V_;
  hipLaunchKernelGGL(lstm_persistent_kernel, dim3(NWG), thr, 0, stream,
                     Wcat, Hbuf, cnt, C0,
                     f_w_xh, i_w_xh, c_w_xh, o_w_xh,
                     f_b, i_b, c_b, o_b,
                     tokens, outH, outH + 65536);

  hipLaunchKernelGGL(out_gemm_kernel, dim3(4096), thr, 0, stream,
                     Hbuf + 65536, ywT, y_b_o, (float*)d_out);
}

// Round 5
// 2063.408 us; speedup vs baseline: 2.7608x; 1.0217x over previous
//
#include <hip/hip_runtime.h>
#include <stdint.h>
#include <stddef.h>

// LSTM: B=64, H=1024, V=4096, T=256
// Phase 0: transpose weights to bf16 k-contiguous layouts (Wcat c=h*4+g, ywT).
// Phase 1: ONE persistent kernel, 128 WGs x 256 thr, all 256 steps.
//   - W-slice (32 gate-cols, 64KB) resident in LDS for the whole kernel
//   - H loads/stores use sc0|sc1 (L2-bypass, coherent via IF cache)
//   - NO grid barrier: 8 per-chunk monotone counters. WG j arrives at
//     counter[j>>4] after its H-slice stores drain; consumers poll
//     counter[c] >= 16*t only right before STAGING chunk c of H_t.
//     Skew is unbounded-safe (H_t slices are distinct buffers).
//   - H streamed via 5-buf LDS ring, lead-4, counted vmcnt, raw s_barrier
//   - waves m-split (wave owns 16 batch rows, full K); C in registers
// Phase 2: one big 16384x4096x1024 bf16 GEMM for Y.
// Workspace: WcatT 8MB | ywT 8MB | Hbuf (257*64*1024 bf16) 33.7MB | cnt 1KB

#define B_ 64
#define H_ 1024
#define V_ 4096
#define T_ 256
#define NWG 128

typedef __attribute__((ext_vector_type(8))) short short8;
typedef __attribute__((ext_vector_type(4))) float f32x4;
typedef __attribute__((ext_vector_type(4))) float float4_;
typedef __attribute__((ext_vector_type(2))) unsigned int uint2v;

static __device__ __forceinline__ unsigned short f2bf(float f) {
  union { float f; unsigned int u; } v; v.f = f;
  unsigned int u = v.u;
  unsigned int r = (u + 0x7fffu + ((u >> 16) & 1u)) >> 16;   // round-to-nearest-even
  return (unsigned short)r;
}

static __device__ __forceinline__ void gload_lds16(const void* g, void* l) {
  // async global->LDS, 16B per lane; LDS dest = wave-uniform base + lane*16
  __builtin_amdgcn_global_load_lds((const __attribute__((address_space(1))) unsigned int*)g,
                                   (__attribute__((address_space(3))) unsigned int*)l,
                                   16, 0, 0);
}
static __device__ __forceinline__ void gload_lds16_sc(const void* g, void* l) {
  // same, with SC0|SC1 (CPol 0x11): bypass L2, read at device coherence point
  __builtin_amdgcn_global_load_lds((const __attribute__((address_space(1))) unsigned int*)g,
                                   (__attribute__((address_space(3))) unsigned int*)l,
                                   16, 0, 17);
}

// ---------------------------------------------------------------------------
// Tiled transpose fp32 (K x C) -> bf16 rows: dst[c = col*c_mul + c_add][k]
// grid: (K/64, C/64), 256 threads
// ---------------------------------------------------------------------------
__global__ void transpose_bf16_kernel(const float* __restrict__ src, int src_cols,
                                      unsigned short* __restrict__ dst,
                                      int c_mul, int c_add) {
  __shared__ float tile[64][65];
  const int k0 = blockIdx.x * 64, h0 = blockIdx.y * 64;
  const int t = threadIdx.x;
  {
    const int kk = t >> 2, seg = (t & 3) * 16;
    const float* s = src + (size_t)(k0 + kk) * src_cols + h0 + seg;
#pragma unroll
    for (int j = 0; j < 16; j += 4) {
      float4_ v = *(const float4_*)(s + j);
      tile[kk][seg + j + 0] = v[0];
      tile[kk][seg + j + 1] = v[1];
      tile[kk][seg + j + 2] = v[2];
      tile[kk][seg + j + 3] = v[3];
    }
  }
  __syncthreads();
  {
    const int hh = t >> 2, ks = (t & 3) * 16;
    const int c = (h0 + hh) * c_mul + c_add;
    short8 p0, p1;
#pragma unroll
    for (int j = 0; j < 8; ++j) {
      p0[j] = (short)f2bf(tile[ks + j][hh]);
      p1[j] = (short)f2bf(tile[ks + 8 + j][hh]);
    }
    unsigned short* d = dst + (size_t)c * 1024 + k0 + ks;
    *(short8*)(d) = p0;
    *(short8*)(d + 8) = p1;
  }
}

// ---------------------------------------------------------------------------
__global__ void init_kernel(const float* __restrict__ H0,
                            unsigned short* __restrict__ Hbuf0,
                            unsigned int* __restrict__ cnt) {
  const int i = blockIdx.x * 256 + threadIdx.x;  // 65536
  Hbuf0[i] = f2bf(H0[i]);
  if (blockIdx.x == 0) cnt[threadIdx.x] = 0;     // zero chunk counters each launch
}

// ---------------------------------------------------------------------------
// Persistent LSTM recurrence. 128 WGs x 256 thr (4 waves).
// LDS: W 64KB @0 | ring 5x16KB @65536 = 144KB.
// ---------------------------------------------------------------------------
#define AOFF 65536

__launch_bounds__(256, 1)
__global__ void lstm_persistent_kernel(
    const unsigned short* __restrict__ Wcat,   // [4096][1024] bf16
    unsigned short* __restrict__ Hbuf,         // [257][64][1024] bf16
    unsigned int* __restrict__ cnt,            // [16*c] = chunk-c counter, c=0..7
    const float* __restrict__ C0,              // [64][1024] f32
    const float* __restrict__ xwf, const float* __restrict__ xwi,
    const float* __restrict__ xwc, const float* __restrict__ xwo,
    const float* __restrict__ bfv, const float* __restrict__ biv,
    const float* __restrict__ bcv, const float* __restrict__ bov,
    const int* __restrict__ tokens,
    float* __restrict__ outH, float* __restrict__ outC) {
  __shared__ __align__(16) unsigned char lds[147456];
  const int tid = threadIdx.x;
  const int wave = tid >> 6, lane = tid & 63;
  const int l15 = lane & 15, l4 = lane >> 4;
  const int wgc0 = blockIdx.x * 32;
  const int hbase0 = wgc0 >> 2;
  const int mychunk = blockIdx.x >> 4;   // h-chunk this WG's H-slice belongs to

  auto xw_of = [&](int g) -> const float* {
    return g == 0 ? xwf : g == 1 ? xwi : g == 2 ? xwc : xwo;
  };
  auto b_of = [&](int g) -> const float* {
    return g == 0 ? bfv : g == 1 ? biv : g == 2 ? bcv : bov;
  };

  // ---- per-lane constants & persistent register state ----
  // output tile element: row(batch) = wave*16 + l4*4 + r, col = wgc0 + ni*16 + l15
  int hh[2], gg[2];
  float bias_v[2], Creg[2][4], xg[2][4], xgn[2][4];
#pragma unroll
  for (int ni = 0; ni < 2; ++ni) {
    const int col = wgc0 + ni * 16 + l15;
    hh[ni] = col >> 2; gg[ni] = col & 3;
    bias_v[ni] = b_of(gg[ni])[hh[ni]];
#pragma unroll
    for (int r = 0; r < 4; ++r)
      Creg[ni][r] = C0[(size_t)(wave * 16 + l4 * 4 + r) * 1024 + hh[ni]];
  }
  {
    int tk[4];
#pragma unroll
    for (int r = 0; r < 4; ++r) tk[r] = tokens[(wave * 16 + l4 * 4 + r) * T_ + 0];
#pragma unroll
    for (int ni = 0; ni < 2; ++ni)
#pragma unroll
      for (int r = 0; r < 4; ++r)
        xg[ni][r] = xw_of(gg[ni])[(size_t)tk[r] * 1024 + hh[ni]];
  }

  // ---- stage W-slice into LDS (once), pre-swizzled source, cached load ----
  {
    const char* Wb = (const char*)(Wcat + (size_t)wgc0 * 1024);
#pragma unroll
    for (int it = 0; it < 16; ++it) {
      const int D = it * 4096 + wave * 1024 + lane * 16;
      const int row = D >> 11, off = D & 2047;
      const int so = off ^ ((row & 7) << 4);
      gload_lds16(Wb + (size_t)row * 2048 + so, &lds[it * 4096 + wave * 1024]);
    }
  }

  auto stageA = [&](int buf, int c, const char* Hsrc) {
#pragma unroll
    for (int it = 0; it < 4; ++it) {
      const int D = it * 4096 + wave * 1024 + lane * 16;
      const int row = D >> 8, off = D & 255;
      const int so = off ^ ((row & 7) << 4);
      gload_lds16_sc(Hsrc + (size_t)row * 2048 + c * 256 + so,
                     &lds[AOFF + buf * 16384 + it * 4096 + wave * 1024]);
    }
  };

  f32x4 acc[2];
  const f32x4 zz = {0.f, 0.f, 0.f, 0.f};

  // prologue A stages for t=0 (chunks 0..3 -> bufs 0..3); H_0 from init_kernel
  stageA(0, 0, (const char*)Hbuf);
  stageA(1, 1, (const char*)Hbuf);
  stageA(2, 2, (const char*)Hbuf);
  stageA(3, 3, (const char*)Hbuf);

  // one-time drain: clears constants/W/prologue so per-iter vmcnt counts hold
  asm volatile("s_waitcnt vmcnt(0)" ::: "memory");
  __syncthreads();

#pragma unroll 1
  for (int t = 0; t < T_; ++t) {
    acc[0] = zz; acc[1] = zz;

    // next-step token loads: issued at step top -> covered by whole K loop.
    // FIFO-safe: extra older loads only make counted vmcnt waits stricter.
    int tok2[4];
    if (t < T_ - 1) {
#pragma unroll
      for (int r = 0; r < 4; ++r)
        tok2[r] = tokens[(wave * 16 + l4 * 4 + r) * T_ + (t + 1)];
    }

    const char* Hs = (const char*)(Hbuf + (size_t)t * 65536);
    const unsigned int tgt_cur = (unsigned int)(16 * t);

    // ---- K loop: 8 chunks of k128, ring-5, lead-4, counted vmcnt ----
    // chunk-c stage is gated by counter[c] >= 16*t (producers of H_t chunk c).
#pragma unroll
    for (int c = 0; c < 8; ++c) {
      if (c < 4 && tid == 0) {
        while (__hip_atomic_load(cnt + 16 * (c + 4), __ATOMIC_RELAXED,
                                 __HIP_MEMORY_SCOPE_AGENT) < tgt_cur) {}
      }
      if (c <= 4)      asm volatile("s_waitcnt vmcnt(12)" ::: "memory");
      else if (c == 5) asm volatile("s_waitcnt vmcnt(8)" ::: "memory");
      else if (c == 6) asm volatile("s_waitcnt vmcnt(4)" ::: "memory");
      else             asm volatile("s_waitcnt vmcnt(0)" ::: "memory");
      __builtin_amdgcn_sched_barrier(0);
      __builtin_amdgcn_s_barrier();     // also gates stageA below on tid0's poll
      __builtin_amdgcn_sched_barrier(0);
      if (c < 4) stageA((c + 4) % 5, c + 4, Hs);
      // compute chunk c from buf c%5: rows wave*16.., cols 0..31, k=c*128..+128
      {
        const int abase = AOFF + (c % 5) * 16384;
        const int arow = wave * 16 + l15;
        const int abyte = abase + arow * 256;
        const int aswz = (arow & 7) << 4;
        const int bswz = (l15 & 7) << 4;
#pragma unroll
        for (int ks = 0; ks < 4; ++ks) {
          const int koff = ks * 64 + l4 * 16;
          short8 a  = *(const short8*)&lds[abyte + (koff ^ aswz)];
          short8 b0 = *(const short8*)&lds[(size_t)l15 * 2048 + ((c * 256 + koff) ^ bswz)];
          short8 b1 = *(const short8*)&lds[(size_t)(16 + l15) * 2048 + ((c * 256 + koff) ^ bswz)];
          acc[0] = __builtin_amdgcn_mfma_f32_16x16x32_bf16(a, b0, acc[0], 0, 0, 0);
          acc[1] = __builtin_amdgcn_mfma_f32_16x16x32_bf16(a, b1, acc[1], 0, 0, 0);
        }
      }
      __builtin_amdgcn_sched_barrier(0);
    }

    // xg for this step: t=0 preloaded; t>0 from prefetch issued last iteration
    if (t > 0) {
#pragma unroll
      for (int ni = 0; ni < 2; ++ni)
#pragma unroll
        for (int r = 0; r < 4; ++r) xg[ni][r] = xgn[ni][r];
    }

    // ---- epilogue: gates on all lanes, C in regs, packed sc0sc1 H store ----
    unsigned short* Hout = Hbuf + (size_t)(t + 1) * 65536;
#pragma unroll
    for (int ni = 0; ni < 2; ++ni) {
#pragma unroll
      for (int r = 0; r < 4; ++r) {
        const float pre = acc[ni][r] + xg[ni][r] + bias_v[ni];
        const float p1 = __shfl_down(pre, 1);
        const float p2 = __shfl_down(pre, 2);
        const float p3 = __shfl_down(pre, 3);
        const float pf = 1.f / (1.f + __expf(-pre));
        const float pi = 1.f / (1.f + __expf(-p1));
        const float e2 = __expf(2.f * p2);
        const float pc = (e2 - 1.f) / (e2 + 1.f);
        const float po = 1.f / (1.f + __expf(-p3));
        const float cn = pf * Creg[ni][r] + pi * pc;   // junk on lanes l15%4!=0: never stored
        Creg[ni][r] = cn;
        const float hv = po * cn;
        const unsigned int sbf = f2bf(hv);
        const unsigned int s4 = __shfl_down(sbf, 4);
        const unsigned int s8 = __shfl_down(sbf, 8);
        const unsigned int s12 = __shfl_down(sbf, 12);
        const int row = wave * 16 + l4 * 4 + r;
        if (l15 == 0) {
          uint2v dat; dat.x = sbf | (s4 << 16); dat.y = s8 | (s12 << 16);
          const unsigned long long addr =
              (unsigned long long)(Hout + (size_t)row * 1024 + hbase0 + ni * 4);
          asm volatile("global_store_dwordx2 %0, %1, off sc0 sc1"
                       :: "v"(addr), "v"(dat) : "memory");
        }
        if (t == T_ - 1 && (lane & 3) == 0) {
          const size_t idx = (size_t)row * 1024 + hh[ni];
          outH[idx] = hv; outC[idx] = cn;
        }
      }
    }

    if (t < T_ - 1) {
      // ---- arrive: this WG's slice of H_{t+1} is globally visible ----
      asm volatile("s_waitcnt vmcnt(0)" ::: "memory");   // H stores drained (per wave)
      __syncthreads();                                    // all waves drained
      if (tid == 0)
        __hip_atomic_fetch_add(cnt + 16 * mychunk, 1u, __ATOMIC_RELAXED,
                               __HIP_MEMORY_SCOPE_AGENT);

      // prefetch next-step x-gather (after arrival so it never delays it)
#pragma unroll
      for (int ni = 0; ni < 2; ++ni)
#pragma unroll
        for (int r = 0; r < 4; ++r)
          xgn[ni][r] = xw_of(gg[ni])[(size_t)tok2[r] * 1024 + hh[ni]];

      // ---- gated prologue stages for t+1 (chunks 0..3) ----
      const unsigned int tgt_next = (unsigned int)(16 * (t + 1));
      if (tid == 0) {
#pragma unroll
        for (int c = 0; c < 4; ++c)
          while (__hip_atomic_load(cnt + 16 * c, __ATOMIC_RELAXED,
                                   __HIP_MEMORY_SCOPE_AGENT) < tgt_next) {}
      }
      __syncthreads();
      const char* Hn = (const char*)(Hbuf + (size_t)(t + 1) * 65536);
      stageA(0, 0, Hn);
      stageA(1, 1, Hn);
      stageA(2, 2, Hn);
      stageA(3, 3, Hn);
    }
  }
}

// ---------------------------------------------------------------------------
// Y = Hseq(16384x1024 bf16) @ ywT^T + bias -> fp32. m97-style 128x128, BK=32.
// grid: 4096 WGs (tm = id>>5, tn = id&31), 256 thr, waves 2x2, wave tile 64x64.
// ---------------------------------------------------------------------------
__launch_bounds__(256, 1)
__global__ void out_gemm_kernel(const unsigned short* __restrict__ A,   // [16384][1024] bf16
                                const unsigned short* __restrict__ Bw,  // ywT [4096][1024] bf16
                                const float* __restrict__ bias,         // [4096]
                                float* __restrict__ Yout) {             // [16384][4096] f32
  __shared__ unsigned char Ash[2][8192];   // 128 rows x 64B, XOR-swizzled
  __shared__ unsigned char Bsh[2][8192];
  const int tid = threadIdx.x;
  const int wave = tid >> 6, lane = tid & 63;
  const int wm = wave >> 1, wn = wave & 1;
  const int bid = blockIdx.x;
  const int tn = bid & 31, tm = bid >> 5;

  const char* Agb = (const char*)(A + (size_t)tm * 128 * 1024);
  const char* Bgb = (const char*)(Bw + (size_t)tn * 128 * 1024);

  f32x4 acc[4][4];
  const f32x4 zz = {0.f, 0.f, 0.f, 0.f};
#pragma unroll
  for (int mi = 0; mi < 4; ++mi)
#pragma unroll
    for (int ni = 0; ni < 4; ++ni) acc[mi][ni] = zz;

  auto stage = [&](int buf, int kc) {
#pragma unroll
    for (int j = 0; j < 2; ++j) {
      const int wbase = wave * 2048 + j * 1024;
      const int D = wbase + lane * 16;
      const int row = D >> 6, off = D & 63;
      const int so = off ^ ((row & 3) << 4);
      gload_lds16(Agb + (size_t)row * 2048 + kc * 64 + so, &Ash[buf][wbase]);
      gload_lds16(Bgb + (size_t)row * 2048 + kc * 64 + so, &Bsh[buf][wbase]);
    }
  };

  stage(0, 0);
  __syncthreads();

#pragma unroll 1
  for (int kc = 0; kc < 32; ++kc) {
    const int cur = kc & 1;
    if (kc < 31) stage(cur ^ 1, kc + 1);
    short8 a[4], b[4];
#pragma unroll
    for (int mi = 0; mi < 4; ++mi) {
      const int row = wm * 64 + mi * 16 + (lane & 15);
      const int off = ((lane >> 4) * 16) ^ ((row & 3) << 4);
      a[mi] = *(const short8*)&Ash[cur][row * 64 + off];
    }
#pragma unroll
    for (int ni = 0; ni < 4; ++ni) {
      const int row = wn * 64 + ni * 16 + (lane & 15);
      const int off = ((lane >> 4) * 16) ^ ((row & 3) << 4);
      b[ni] = *(const short8*)&Bsh[cur][row * 64 + off];
    }
#pragma unroll
    for (int mi = 0; mi < 4; ++mi)
#pragma unroll
      for (int ni = 0; ni < 4; ++ni)
        acc[mi][ni] = __builtin_amdgcn_mfma_f32_16x16x32_bf16(a[mi], b[ni], acc[mi][ni], 0, 0, 0);
    __syncthreads();
  }

  const int l15 = lane & 15, l4 = lane >> 4;
#pragma unroll
  for (int ni = 0; ni < 4; ++ni) {
    const int n = tn * 128 + wn * 64 + ni * 16 + l15;
    const float bv = bias[n];
#pragma unroll
    for (int mi = 0; mi < 4; ++mi) {
#pragma unroll
      for (int r = 0; r < 4; ++r) {
        const int m = tm * 128 + wm * 64 + mi * 16 + l4 * 4 + r;
        Yout[(size_t)m * 4096 + n] = acc[mi][ni][r] + bv;
      }
    }
  }
}

// ---------------------------------------------------------------------------
extern "C" void kernel_launch(void* const* d_in, const int* in_sizes, int n_in,
                              void* d_out, int out_size, void* d_ws, size_t ws_size,
                              hipStream_t stream) {
  const int* tokens   = (const int*)d_in[0];
  const float* H0     = (const float*)d_in[1];
  const float* C0     = (const float*)d_in[2];
  const float* f_w_xh = (const float*)d_in[3];
  const float* f_w_hh = (const float*)d_in[4];
  const float* f_b    = (const float*)d_in[5];
  const float* i_w_xh = (const float*)d_in[6];
  const float* i_w_hh = (const float*)d_in[7];
  const float* i_b    = (const float*)d_in[8];
  const float* c_w_xh = (const float*)d_in[9];
  const float* c_w_hh = (const float*)d_in[10];
  const float* c_b    = (const float*)d_in[11];
  const float* o_w_xh = (const float*)d_in[12];
  const float* o_w_hh = (const float*)d_in[13];
  const float* o_b    = (const float*)d_in[14];
  const float* y_w_ho = (const float*)d_in[15];
  const float* y_b_o  = (const float*)d_in[16];

  char* ws = (char*)d_ws;
  unsigned short* Wcat = (unsigned short*)ws;                         // 8 MB
  unsigned short* ywT  = (unsigned short*)(ws + (size_t)(8u << 20));  // 8 MB
  unsigned short* Hbuf = (unsigned short*)(ws + (size_t)(16u << 20)); // 257*65536*2 B
  unsigned int* cnt = (unsigned int*)(ws + (size_t)(16u << 20) + (size_t)257 * 65536 * 2);
  const size_t needed = (size_t)(16u << 20) + (size_t)257 * 65536 * 2 + 1024;
  if (ws_size < needed) return;  // workspace too small: fail visibly

  const dim3 thr(256);
  hipLaunchKernelGGL(transpose_bf16_kernel, dim3(16, 16), thr, 0, stream, f_w_hh, 1024, Wcat, 4, 0);
  hipLaunchKernelGGL(transpose_bf16_kernel, dim3(16, 16), thr, 0, stream, i_w_hh, 1024, Wcat, 4, 1);
  hipLaunchKernelGGL(transpose_bf16_kernel, dim3(16, 16), thr, 0, stream, c_w_hh, 1024, Wcat, 4, 2);
  hipLaunchKernelGGL(transpose_bf16_kernel, dim3(16, 16), thr, 0, stream, o_w_hh, 1024, Wcat, 4, 3);
  hipLaunchKernelGGL(transpose_bf16_kernel, dim3(16, 64), thr, 0, stream, y_w_ho, 4096, ywT, 1, 0);
  hipLaunchKernelGGL(init_kernel, dim3(256), thr, 0, stream, H0, Hbuf, cnt);

  float* outH = (float*)d_out + (size_t)T_ * B_ * V_;
  hipLaunchKernelGGL(lstm_persistent_kernel, dim3(NWG), thr, 0, stream,
                     Wcat, Hbuf, cnt, C0,
                     f_w_xh, i_w_xh, c_w_xh, o_w_xh,
                     f_b, i_b, c_b, o_b,
                     tokens, outH, outH + 65536);

  hipLaunchKernelGGL(out_gemm_kernel, dim3(4096), thr, 0, stream,
                     Hbuf + 65536, ywT, y_b_o, (float*)d_out);
}